// Round 1
// baseline (1563.759 us; speedup 1.0000x reference)
//
#include <hip/hip_runtime.h>
#include <hip/hip_bf16.h>
#include <math.h>

// AURA block: x = x + Mix(RMSNorm(x)); x = x + SwiGLU(RMSNorm(x))
// Shapes: B=2, T=1024, D=1024, H=16, HD=64, chunk L=128, N=8 chunks, HIDDEN=4096.
// Round 0: correctness-first fp32 implementation.

#define DIMD 1024
#define BT   2048          // B*T rows
#define HEADS 16
#define HD   64
#define CHUNK 128
#define NCHUNK 8
#define HIDDEN 4096
#define DECAYF 0.9f
#define WL_128 1.3900845e-06f   // 0.9^128 (double-computed, rounded to f32)

// ---------------- RMSNorm ----------------
__global__ __launch_bounds__(256) void rmsnorm_kernel(const float* __restrict__ x,
                                                      const float* __restrict__ w,
                                                      float* __restrict__ out) {
    int row = blockIdx.x;
    const float* xr = x + (size_t)row * DIMD;
    int i0 = threadIdx.x * 4;
    float4 v = *reinterpret_cast<const float4*>(xr + i0);
    float ss = v.x*v.x + v.y*v.y + v.z*v.z + v.w*v.w;
    #pragma unroll
    for (int off = 32; off; off >>= 1) ss += __shfl_xor(ss, off);
    __shared__ float red[4];
    if ((threadIdx.x & 63) == 0) red[threadIdx.x >> 6] = ss;
    __syncthreads();
    ss = red[0] + red[1] + red[2] + red[3];
    float norm = rsqrtf(ss * (1.0f / DIMD) + 1e-5f);
    float4 wv = *reinterpret_cast<const float4*>(w + i0);
    float4 o;
    o.x = wv.x * v.x * norm;
    o.y = wv.y * v.y * norm;
    o.z = wv.z * v.z * norm;
    o.w = wv.w * v.w * norm;
    *reinterpret_cast<float4*>(out + (size_t)row * DIMD + i0) = o;
}

// ---------------- generic fp32 GEMM: C = A@B (+add) (+activation) ----------------
// act: 0 = none, 1 = sigmoid
__global__ __launch_bounds__(256) void gemm_f32(const float* __restrict__ A,
                                                const float* __restrict__ B,
                                                float* __restrict__ C,
                                                const float* __restrict__ add,
                                                int M, int N, int K, int act) {
    __shared__ float As[16][65];
    __shared__ float Bs[16][65];
    int bm = blockIdx.y << 6, bn = blockIdx.x << 6;
    int tid = threadIdx.x;
    int tr = tid >> 4, tc = tid & 15;
    float acc[4][4] = {};
    for (int k0 = 0; k0 < K; k0 += 16) {
        #pragma unroll
        for (int i = 0; i < 4; ++i) {
            int idx = tid + (i << 8);
            int row = idx >> 4, kk = idx & 15;
            As[kk][row] = A[(size_t)(bm + row) * K + k0 + kk];
            int kk2 = idx >> 6, col = idx & 63;
            Bs[kk2][col] = B[(size_t)(k0 + kk2) * N + bn + col];
        }
        __syncthreads();
        #pragma unroll
        for (int kk = 0; kk < 16; ++kk) {
            float a[4], bb[4];
            #pragma unroll
            for (int i = 0; i < 4; ++i) a[i] = As[kk][(tr << 2) + i];
            #pragma unroll
            for (int j = 0; j < 4; ++j) bb[j] = Bs[kk][(tc << 2) + j];
            #pragma unroll
            for (int i = 0; i < 4; ++i)
                #pragma unroll
                for (int j = 0; j < 4; ++j) acc[i][j] += a[i] * bb[j];
        }
        __syncthreads();
    }
    #pragma unroll
    for (int i = 0; i < 4; ++i) {
        int rrow = bm + (tr << 2) + i;
        #pragma unroll
        for (int j = 0; j < 4; ++j) {
            int ccol = bn + (tc << 2) + j;
            float vv = acc[i][j];
            if (act == 1) vv = 1.0f / (1.0f + expf(-vv));
            size_t o = (size_t)rrow * N + ccol;
            if (add) vv += add[o];
            C[o] = vv;
        }
    }
}

// ---------------- dual GEMM + SwiGLU epilogue: C = silu(A@B1) * (A@B2) ----------------
__global__ __launch_bounds__(256) void gemm_swiglu(const float* __restrict__ A,
                                                   const float* __restrict__ B1,
                                                   const float* __restrict__ B2,
                                                   float* __restrict__ C,
                                                   int M, int N, int K) {
    __shared__ float As[16][65];
    __shared__ float Bs1[16][65];
    __shared__ float Bs2[16][65];
    int bm = blockIdx.y << 6, bn = blockIdx.x << 6;
    int tid = threadIdx.x;
    int tr = tid >> 4, tc = tid & 15;
    float acc1[4][4] = {};
    float acc2[4][4] = {};
    for (int k0 = 0; k0 < K; k0 += 16) {
        #pragma unroll
        for (int i = 0; i < 4; ++i) {
            int idx = tid + (i << 8);
            int row = idx >> 4, kk = idx & 15;
            As[kk][row] = A[(size_t)(bm + row) * K + k0 + kk];
            int kk2 = idx >> 6, col = idx & 63;
            Bs1[kk2][col] = B1[(size_t)(k0 + kk2) * N + bn + col];
            Bs2[kk2][col] = B2[(size_t)(k0 + kk2) * N + bn + col];
        }
        __syncthreads();
        #pragma unroll
        for (int kk = 0; kk < 16; ++kk) {
            float a[4], b1[4], b2[4];
            #pragma unroll
            for (int i = 0; i < 4; ++i) a[i] = As[kk][(tr << 2) + i];
            #pragma unroll
            for (int j = 0; j < 4; ++j) b1[j] = Bs1[kk][(tc << 2) + j];
            #pragma unroll
            for (int j = 0; j < 4; ++j) b2[j] = Bs2[kk][(tc << 2) + j];
            #pragma unroll
            for (int i = 0; i < 4; ++i)
                #pragma unroll
                for (int j = 0; j < 4; ++j) {
                    acc1[i][j] += a[i] * b1[j];
                    acc2[i][j] += a[i] * b2[j];
                }
        }
        __syncthreads();
    }
    #pragma unroll
    for (int i = 0; i < 4; ++i) {
        int rrow = bm + (tr << 2) + i;
        #pragma unroll
        for (int j = 0; j < 4; ++j) {
            int ccol = bn + (tc << 2) + j;
            float a = acc1[i][j];
            float g = a / (1.0f + expf(-a)) * acc2[i][j];
            C[(size_t)rrow * N + ccol] = g;
        }
    }
}

// ---------------- spike threshold + k-winners-take-all (per token, per head) ----------------
__global__ __launch_bounds__(256) void kwta_kernel(float* __restrict__ k, int total) {
    int wid = (int)((blockIdx.x * (size_t)blockDim.x + threadIdx.x) >> 6);
    int lane = threadIdx.x & 63;
    if (wid >= total) return;
    float* base = k + (size_t)wid * HD;
    float v = base[lane];
    float val = (v > 0.5f) ? v : 0.0f;
    float cur = val;
    float thr = 0.0f;
    #pragma unroll
    for (int it = 0; it < 4; ++it) {
        float m = cur;
        #pragma unroll
        for (int off = 32; off; off >>= 1) m = fmaxf(m, __shfl_xor(m, off));
        thr = m;
        unsigned long long ball = __ballot(cur == m);
        int leader = __ffsll((unsigned long long)ball) - 1;
        if (lane == leader) cur = -1.0f;
    }
    base[lane] = (val >= thr) ? val : 0.0f;
}

// ---------------- attention pass A: per-chunk state contribution C_n[d][e] ----------------
// blockIdx.x = n*32 + b*16 + h
__global__ __launch_bounds__(256) void attn_state_kernel(const float* __restrict__ k,
                                                         const float* __restrict__ v,
                                                         float* __restrict__ Cbuf) {
    int n = blockIdx.x >> 5;
    int bh = blockIdx.x & 31;
    int b = bh >> 4, hh = bh & 15;
    __shared__ float ks[CHUNK][HD + 1];
    __shared__ float vs[CHUNK][HD + 1];
    __shared__ float pw[CHUNK + 1];
    int tid = threadIdx.x;
    if (tid < CHUNK + 1) pw[tid] = powf(DECAYF, (float)tid);
    __syncthreads();
    #pragma unroll
    for (int i = 0; i < 32; ++i) {
        int idx = tid + (i << 8);
        int l = idx >> 6, d = idx & 63;
        size_t g = (((size_t)(b * 1024 + n * CHUNK + l)) * HEADS + hh) * HD + d;
        ks[l][d] = k[g] * pw[CHUNK - 1 - l];  // w_out[l] = decay^(127-l)
        vs[l][d] = v[g];
    }
    __syncthreads();
    int d = tid >> 2;
    int e0 = (tid & 3) << 4;
    float acc[16] = {};
    for (int l = 0; l < CHUNK; ++l) {
        float kv = ks[l][d];
        #pragma unroll
        for (int j = 0; j < 16; ++j) acc[j] += kv * vs[l][e0 + j];
    }
    size_t off = (size_t)blockIdx.x * 4096 + d * 64 + e0;
    #pragma unroll
    for (int j = 0; j < 16; ++j) Cbuf[off + j] = acc[j];
}

// ---------------- attention pass B: prefix scan of states across chunks ----------------
// blockIdx.x = b*16 + h  (32 blocks); S_0 = 0; S_{n+1} = wL*S_n + C_n
__global__ __launch_bounds__(256) void attn_scan_kernel(const float* __restrict__ Cbuf,
                                                        float* __restrict__ Sbuf) {
    int bh = blockIdx.x;
    int tid = threadIdx.x;
    float S[16];
    #pragma unroll
    for (int j = 0; j < 16; ++j) S[j] = 0.0f;
    for (int n = 0; n < NCHUNK; ++n) {
        size_t off = ((size_t)(n * 32 + bh)) * 4096 + tid * 16;
        #pragma unroll
        for (int j = 0; j < 16; ++j) Sbuf[off + j] = S[j];
        #pragma unroll
        for (int j = 0; j < 16; ++j) S[j] = WL_128 * S[j] + Cbuf[off + j];
    }
}

// ---------------- attention pass C: y = inter + intra ----------------
// blockIdx.x = n*32 + b*16 + h
__global__ __launch_bounds__(256) void attn_out_kernel(const float* __restrict__ r,
                                                       const float* __restrict__ k,
                                                       const float* __restrict__ v,
                                                       const float* __restrict__ Sbuf,
                                                       float* __restrict__ y) {
    int n = blockIdx.x >> 5;
    int bh = blockIdx.x & 31;
    int b = bh >> 4, hh = bh & 15;
    __shared__ float rs[CHUNK][HD + 1];
    __shared__ float ks[CHUNK][HD + 1];
    __shared__ float vs[CHUNK][HD + 1];
    __shared__ float Ss[HD][HD + 1];
    __shared__ float pw[CHUNK + 1];
    int tid = threadIdx.x;
    if (tid < CHUNK + 1) pw[tid] = powf(DECAYF, (float)tid);
    #pragma unroll
    for (int i = 0; i < 32; ++i) {
        int idx = tid + (i << 8);
        int l = idx >> 6, d = idx & 63;
        size_t g = (((size_t)(b * 1024 + n * CHUNK + l)) * HEADS + hh) * HD + d;
        rs[l][d] = r[g];
        ks[l][d] = k[g];
        vs[l][d] = v[g];
    }
    {
        size_t soff = (size_t)blockIdx.x * 4096;
        #pragma unroll
        for (int i = 0; i < 16; ++i) {
            int idx = tid + (i << 8);
            Ss[idx >> 6][idx & 63] = Sbuf[soff + idx];
        }
    }
    __syncthreads();
    int l = tid >> 1;
    int e0 = (tid & 1) << 5;
    float acc[32] = {};
    // inter: (r[l]*w_in[l]) @ S
    for (int d2 = 0; d2 < HD; ++d2) {
        float rv = rs[l][d2];
        #pragma unroll
        for (int j = 0; j < 32; ++j) acc[j] += rv * Ss[d2][e0 + j];
    }
    float win = pw[l + 1];
    #pragma unroll
    for (int j = 0; j < 32; ++j) acc[j] *= win;
    // intra: sum_{m<=l} (r[l].k[m]) * decay^(l-m) * v[m]
    for (int m = 0; m <= l; ++m) {
        float a = 0.0f;
        #pragma unroll
        for (int d2 = 0; d2 < HD; ++d2) a += rs[l][d2] * ks[m][d2];
        a *= pw[l - m];
        #pragma unroll
        for (int j = 0; j < 32; ++j) acc[j] += a * vs[m][e0 + j];
    }
    size_t g = (((size_t)(b * 1024 + n * CHUNK + l)) * HEADS + hh) * HD + e0;
    #pragma unroll
    for (int j = 0; j < 32; ++j) y[g + j] = acc[j];
}

extern "C" void kernel_launch(void* const* d_in, const int* in_sizes, int n_in,
                              void* d_out, int out_size, void* d_ws, size_t ws_size,
                              hipStream_t stream) {
    const float* x      = (const float*)d_in[0];
    const float* norm1w = (const float*)d_in[1];
    const float* Wr     = (const float*)d_in[2];
    const float* Wk     = (const float*)d_in[3];
    const float* Wv     = (const float*)d_in[4];
    const float* Wo     = (const float*)d_in[5];
    const float* norm2w = (const float*)d_in[6];
    const float* w1     = (const float*)d_in[7];
    const float* w2     = (const float*)d_in[8];
    const float* w3     = (const float*)d_in[9];
    float* out = (float*)d_out;

    float* ws = (float*)d_ws;
    const size_t MSZ = (size_t)BT * DIMD;      // 2M floats
    float* h   = ws;                            // [0, 2M)
    float* r   = ws + 2 * MSZ / 2;              // keep simple: offsets in floats
    // Explicit offsets (floats):
    float* hbuf = ws + 0;                       // 2M
    float* rbuf = ws + 2 * 1024 * 1024;         // 2M
    float* kbuf = ws + 4 * 1024 * 1024;         // 2M
    float* vbuf = ws + 6 * 1024 * 1024;         // 2M
    float* ybuf = ws + 8 * 1024 * 1024;         // 2M
    float* Cbuf = ws + 10 * 1024 * 1024;        // 1M
    float* Sbuf = ws + 11 * 1024 * 1024;        // 1M
    float* gbuf = ws + 2 * 1024 * 1024;         // reuse r..y region: 8M floats
    (void)h; (void)r; (void)in_sizes; (void)n_in; (void)out_size; (void)ws_size;

    dim3 blk(256);

    // 1. h = rmsnorm(x, norm1)
    rmsnorm_kernel<<<BT, blk, 0, stream>>>(x, norm1w, hbuf);
    // 2. r = sigmoid(h @ Wr)
    gemm_f32<<<dim3(DIMD / 64, BT / 64), blk, 0, stream>>>(hbuf, Wr, rbuf, nullptr, BT, DIMD, DIMD, 1);
    // 3. k = h @ Wk
    gemm_f32<<<dim3(DIMD / 64, BT / 64), blk, 0, stream>>>(hbuf, Wk, kbuf, nullptr, BT, DIMD, DIMD, 0);
    // 4. spike + kWTA on k (in place)
    kwta_kernel<<<(BT * HEADS) / 4, blk, 0, stream>>>(kbuf, BT * HEADS);
    // 5. v = h @ Wv
    gemm_f32<<<dim3(DIMD / 64, BT / 64), blk, 0, stream>>>(hbuf, Wv, vbuf, nullptr, BT, DIMD, DIMD, 0);
    // 6. per-chunk state contributions
    attn_state_kernel<<<NCHUNK * 32, blk, 0, stream>>>(kbuf, vbuf, Cbuf);
    // 7. prefix scan of states
    attn_scan_kernel<<<32, blk, 0, stream>>>(Cbuf, Sbuf);
    // 8. attention outputs
    attn_out_kernel<<<NCHUNK * 32, blk, 0, stream>>>(rbuf, kbuf, vbuf, Sbuf, ybuf);
    // 9. x1 = x + y @ Wo  -> d_out
    gemm_f32<<<dim3(DIMD / 64, BT / 64), blk, 0, stream>>>(ybuf, Wo, out, x, BT, DIMD, DIMD, 0);
    // 10. h = rmsnorm(x1, norm2)
    rmsnorm_kernel<<<BT, blk, 0, stream>>>(out, norm2w, hbuf);
    // 11. g = silu(h@w1) * (h@w2)
    gemm_swiglu<<<dim3(HIDDEN / 64, BT / 64), blk, 0, stream>>>(hbuf, w1, w2, gbuf, BT, HIDDEN, DIMD);
    // 12. out = out + g @ w3
    gemm_f32<<<dim3(DIMD / 64, BT / 64), blk, 0, stream>>>(gbuf, w3, out, out, BT, DIMD, HIDDEN, 0);
}

// Round 3
// 454.363 us; speedup vs baseline: 3.4417x; 3.4417x over previous
//
#include <hip/hip_runtime.h>
#include <hip/hip_bf16.h>
#include <math.h>

// AURA block. B=2, T=1024, D=1024, H=16, HD=64, chunk L=128, N=8, HIDDEN=4096.
// Round 3: bf16 MFMA GEMMs (m97-style, swizzled LDS, global_load_lds) for all
// precision-insensitive GEMMs; Wk projection stays fp32 (kWTA threshold path).
// Fix vs R2: __hip_bfloat16 has no .data member -> __builtin_bit_cast helpers.

#define DIMD 1024
#define BT   2048
#define HEADS 16
#define HD   64
#define CHUNK 128
#define NCHUNK 8
#define HIDDEN 4096
#define DECAYF 0.9f
#define WL_128 1.3900845e-06f   // 0.9^128

typedef __attribute__((ext_vector_type(4))) float f32x4;
typedef __attribute__((ext_vector_type(8))) short bf16x8;

__device__ __forceinline__ unsigned short f2bf(float f) {
    __hip_bfloat16 h = __float2bfloat16(f);
    return __builtin_bit_cast(unsigned short, h);
}
__device__ __forceinline__ float bf2f(unsigned short u) {
    __hip_bfloat16 h = __builtin_bit_cast(__hip_bfloat16, u);
    return __bfloat162float(h);
}

__device__ __forceinline__ void gload_lds16(const void* g, void* l) {
    __builtin_amdgcn_global_load_lds(
        (const __attribute__((address_space(1))) void*)g,
        (__attribute__((address_space(3))) void*)l,
        16, 0, 0);
}

// ---------------- RMSNorm (fp32 out optional, bf16 out optional) ----------------
__global__ __launch_bounds__(256) void rmsnorm_kernel(const float* __restrict__ x,
                                                      const float* __restrict__ w,
                                                      float* __restrict__ out32,
                                                      unsigned short* __restrict__ out16) {
    int row = blockIdx.x;
    const float* xr = x + (size_t)row * DIMD;
    int i0 = threadIdx.x * 4;
    float4 v = *reinterpret_cast<const float4*>(xr + i0);
    float ss = v.x*v.x + v.y*v.y + v.z*v.z + v.w*v.w;
    #pragma unroll
    for (int off = 32; off; off >>= 1) ss += __shfl_xor(ss, off);
    __shared__ float red[4];
    if ((threadIdx.x & 63) == 0) red[threadIdx.x >> 6] = ss;
    __syncthreads();
    ss = red[0] + red[1] + red[2] + red[3];
    float norm = rsqrtf(ss * (1.0f / DIMD) + 1e-5f);
    float4 wv = *reinterpret_cast<const float4*>(w + i0);
    float o[4];
    o[0] = wv.x * v.x * norm; o[1] = wv.y * v.y * norm;
    o[2] = wv.z * v.z * norm; o[3] = wv.w * v.w * norm;
    if (out32) {
        float4 f; f.x = o[0]; f.y = o[1]; f.z = o[2]; f.w = o[3];
        *reinterpret_cast<float4*>(out32 + (size_t)row * DIMD + i0) = f;
    }
    if (out16) {
        ushort4 u;
        u.x = f2bf(o[0]); u.y = f2bf(o[1]); u.z = f2bf(o[2]); u.w = f2bf(o[3]);
        *reinterpret_cast<ushort4*>(out16 + (size_t)row * DIMD + i0) = u;
    }
}

// ---------------- transpose + fp32->bf16 weight conversion: dst[N][K] = src[K][N] ----------------
__global__ __launch_bounds__(256) void transpose_cvt(const float* __restrict__ src,
                                                     unsigned short* __restrict__ dst,
                                                     int K, int N) {
    __shared__ float t[32][33];
    int bn = blockIdx.x * 32, bk = blockIdx.y * 32;
    int tx = threadIdx.x & 31, ty = threadIdx.x >> 5;   // ty 0..7
    #pragma unroll
    for (int i = 0; i < 32; i += 8)
        t[ty + i][tx] = src[(size_t)(bk + ty + i) * N + bn + tx];
    __syncthreads();
    #pragma unroll
    for (int i = 0; i < 32; i += 8)
        dst[(size_t)(bn + ty + i) * K + bk + tx] = f2bf(t[tx][ty + i]);
}

// ---------------- bf16 MFMA GEMM: C[M,N] = A[M,K] @ Bt[N,K]^T ----------------
// EPI: 0 = fp32 out, 1 = sigmoid fp32 out, 2 = +add fp32 out, 3 = bf16 out
template <int EPI>
__global__ __launch_bounds__(256) void gemm_bf16(const unsigned short* __restrict__ A,
                                                 const unsigned short* __restrict__ Bt,
                                                 void* __restrict__ Cout,
                                                 const float* __restrict__ add,
                                                 int M, int N, int K) {
    __shared__ __align__(16) short As[128 * 64];
    __shared__ __align__(16) short Bs[128 * 64];
    const int tid = threadIdx.x;
    const int wv = tid >> 6, ln = tid & 63;
    const int bm = blockIdx.y << 7, bn = blockIdx.x << 7;
    const int wr = (wv >> 1) << 6, wc = (wv & 1) << 6;   // wave's 64x64 sub-tile
    const int g = ln >> 4, r16 = ln & 15;

    f32x4 acc[4][4];
    #pragma unroll
    for (int i = 0; i < 4; ++i)
        #pragma unroll
        for (int j = 0; j < 4; ++j) acc[i][j] = (f32x4){0.f, 0.f, 0.f, 0.f};

    const short* Ag = (const short*)A;
    const short* Bg = (const short*)Bt;
    // staging geometry: per issue, wave writes one 1024B chunk (8 rows of 128B)
    const int srow_off = ln >> 3;          // 0..7 within chunk
    const int sslot = ln & 7;              // physical 16B slot in row
    for (int k0 = 0; k0 < K; k0 += 64) {
        #pragma unroll
        for (int i = 0; i < 4; ++i) {
            int c = wv * 4 + i;
            int row = c * 8 + srow_off;
            int kcol = ((sslot ^ (row & 7)) << 3);           // inverse-swizzled source
            gload_lds16(Ag + (size_t)(bm + row) * K + k0 + kcol, &As[c * 512 + ln * 8]);
            gload_lds16(Bg + (size_t)(bn + row) * K + k0 + kcol, &Bs[c * 512 + ln * 8]);
        }
        __syncthreads();
        #pragma unroll
        for (int kk = 0; kk < 2; ++kk) {
            bf16x8 af[4], bfr[4];
            #pragma unroll
            for (int mi = 0; mi < 4; ++mi) {
                int row = wr + mi * 16 + r16;
                int slot = (kk * 4 + g) ^ (row & 7);
                af[mi] = *reinterpret_cast<const bf16x8*>(&As[row * 64 + slot * 8]);
            }
            #pragma unroll
            for (int ni = 0; ni < 4; ++ni) {
                int row = wc + ni * 16 + r16;
                int slot = (kk * 4 + g) ^ (row & 7);
                bfr[ni] = *reinterpret_cast<const bf16x8*>(&Bs[row * 64 + slot * 8]);
            }
            #pragma unroll
            for (int mi = 0; mi < 4; ++mi)
                #pragma unroll
                for (int ni = 0; ni < 4; ++ni)
                    acc[mi][ni] = __builtin_amdgcn_mfma_f32_16x16x32_bf16(
                        af[mi], bfr[ni], acc[mi][ni], 0, 0, 0);
        }
        __syncthreads();
    }
    // epilogue: C row = (lane>>4)*4 + q, col = lane&15 within each 16x16 frag
    #pragma unroll
    for (int mi = 0; mi < 4; ++mi) {
        #pragma unroll
        for (int q = 0; q < 4; ++q) {
            int row = bm + wr + mi * 16 + g * 4 + q;
            #pragma unroll
            for (int ni = 0; ni < 4; ++ni) {
                int col = bn + wc + ni * 16 + r16;
                float vv = acc[mi][ni][q];
                size_t o = (size_t)row * N + col;
                if (EPI == 1) vv = 1.0f / (1.0f + expf(-vv));
                if (EPI == 2) vv += add[o];
                if (EPI == 3) ((unsigned short*)Cout)[o] = f2bf(vv);
                else          ((float*)Cout)[o] = vv;
            }
        }
    }
}

// ---------------- fp32 GEMM (Wk path only): C = A@B ----------------
__global__ __launch_bounds__(256) void gemm_f32(const float* __restrict__ A,
                                                const float* __restrict__ B,
                                                float* __restrict__ C,
                                                int M, int N, int K) {
    __shared__ float As[16][65];
    __shared__ float Bs[16][65];
    int bm = blockIdx.y << 6, bn = blockIdx.x << 6;
    int tid = threadIdx.x;
    int tr = tid >> 4, tc = tid & 15;
    float acc[4][4] = {};
    for (int k0 = 0; k0 < K; k0 += 16) {
        #pragma unroll
        for (int i = 0; i < 4; ++i) {
            int idx = tid + (i << 8);
            int row = idx >> 4, kk = idx & 15;
            As[kk][row] = A[(size_t)(bm + row) * K + k0 + kk];
            int kk2 = idx >> 6, col = idx & 63;
            Bs[kk2][col] = B[(size_t)(k0 + kk2) * N + bn + col];
        }
        __syncthreads();
        #pragma unroll
        for (int kk = 0; kk < 16; ++kk) {
            float a[4], bb[4];
            #pragma unroll
            for (int i = 0; i < 4; ++i) a[i] = As[kk][(tr << 2) + i];
            #pragma unroll
            for (int j = 0; j < 4; ++j) bb[j] = Bs[kk][(tc << 2) + j];
            #pragma unroll
            for (int i = 0; i < 4; ++i)
                #pragma unroll
                for (int j = 0; j < 4; ++j) acc[i][j] += a[i] * bb[j];
        }
        __syncthreads();
    }
    #pragma unroll
    for (int i = 0; i < 4; ++i)
        #pragma unroll
        for (int j = 0; j < 4; ++j)
            C[(size_t)(bm + (tr << 2) + i) * N + bn + (tc << 2) + j] = acc[i][j];
}

// ---------------- spike threshold + k-winners-take-all ----------------
__global__ __launch_bounds__(256) void kwta_kernel(float* __restrict__ k, int total) {
    int wid = (int)((blockIdx.x * (size_t)blockDim.x + threadIdx.x) >> 6);
    int lane = threadIdx.x & 63;
    if (wid >= total) return;
    float* base = k + (size_t)wid * HD;
    float v = base[lane];
    float val = (v > 0.5f) ? v : 0.0f;
    float cur = val;
    float thr = 0.0f;
    #pragma unroll
    for (int it = 0; it < 4; ++it) {
        float m = cur;
        #pragma unroll
        for (int off = 32; off; off >>= 1) m = fmaxf(m, __shfl_xor(m, off));
        thr = m;
        unsigned long long ball = __ballot(cur == m);
        int leader = __ffsll((unsigned long long)ball) - 1;
        if (lane == leader) cur = -1.0f;
    }
    base[lane] = (val >= thr) ? val : 0.0f;
}

// ---------------- attention pass A: per-chunk state contribution ----------------
__global__ __launch_bounds__(256) void attn_state_kernel(const float* __restrict__ k,
                                                         const float* __restrict__ v,
                                                         float* __restrict__ Cbuf) {
    int n = blockIdx.x >> 5;
    int bh = blockIdx.x & 31;
    int b = bh >> 4, hh = bh & 15;
    __shared__ float ks[CHUNK][HD + 1];
    __shared__ float vs[CHUNK][HD + 1];
    __shared__ float pw[CHUNK + 1];
    int tid = threadIdx.x;
    if (tid < CHUNK + 1) pw[tid] = powf(DECAYF, (float)tid);
    __syncthreads();
    #pragma unroll
    for (int i = 0; i < 32; ++i) {
        int idx = tid + (i << 8);
        int l = idx >> 6, d = idx & 63;
        size_t gg = (((size_t)(b * 1024 + n * CHUNK + l)) * HEADS + hh) * HD + d;
        ks[l][d] = k[gg] * pw[CHUNK - 1 - l];
        vs[l][d] = v[gg];
    }
    __syncthreads();
    int d = tid >> 2;
    int e0 = (tid & 3) << 4;
    float acc[16] = {};
    for (int l = 0; l < CHUNK; ++l) {
        float kv = ks[l][d];
        #pragma unroll
        for (int j = 0; j < 16; ++j) acc[j] += kv * vs[l][e0 + j];
    }
    size_t off = (size_t)blockIdx.x * 4096 + d * 64 + e0;
    #pragma unroll
    for (int j = 0; j < 16; ++j) Cbuf[off + j] = acc[j];
}

// ---------------- attention pass B: prefix scan of states ----------------
__global__ __launch_bounds__(256) void attn_scan_kernel(const float* __restrict__ Cbuf,
                                                        float* __restrict__ Sbuf) {
    int bh = blockIdx.x;
    int tid = threadIdx.x;
    float S[16];
    #pragma unroll
    for (int j = 0; j < 16; ++j) S[j] = 0.0f;
    for (int n = 0; n < NCHUNK; ++n) {
        size_t off = ((size_t)(n * 32 + bh)) * 4096 + tid * 16;
        #pragma unroll
        for (int j = 0; j < 16; ++j) Sbuf[off + j] = S[j];
        #pragma unroll
        for (int j = 0; j < 16; ++j) S[j] = WL_128 * S[j] + Cbuf[off + j];
    }
}

// ---------------- attention pass C: y = inter + intra (bf16 out) ----------------
__global__ __launch_bounds__(256) void attn_out_kernel(const float* __restrict__ r,
                                                       const float* __restrict__ k,
                                                       const float* __restrict__ v,
                                                       const float* __restrict__ Sbuf,
                                                       unsigned short* __restrict__ y) {
    int n = blockIdx.x >> 5;
    int bh = blockIdx.x & 31;
    int b = bh >> 4, hh = bh & 15;
    __shared__ float rs[CHUNK][HD + 1];
    __shared__ float ks[CHUNK][HD + 1];
    __shared__ float vs[CHUNK][HD + 1];
    __shared__ float Ss[HD][HD + 1];
    __shared__ float pw[CHUNK + 1];
    int tid = threadIdx.x;
    if (tid < CHUNK + 1) pw[tid] = powf(DECAYF, (float)tid);
    #pragma unroll
    for (int i = 0; i < 32; ++i) {
        int idx = tid + (i << 8);
        int l = idx >> 6, d = idx & 63;
        size_t gg = (((size_t)(b * 1024 + n * CHUNK + l)) * HEADS + hh) * HD + d;
        rs[l][d] = r[gg];
        ks[l][d] = k[gg];
        vs[l][d] = v[gg];
    }
    {
        size_t soff = (size_t)blockIdx.x * 4096;
        #pragma unroll
        for (int i = 0; i < 16; ++i) {
            int idx = tid + (i << 8);
            Ss[idx >> 6][idx & 63] = Sbuf[soff + idx];
        }
    }
    __syncthreads();
    int l = tid >> 1;
    int e0 = (tid & 1) << 5;
    float acc[32] = {};
    for (int d2 = 0; d2 < HD; ++d2) {
        float rv = rs[l][d2];
        #pragma unroll
        for (int j = 0; j < 32; ++j) acc[j] += rv * Ss[d2][e0 + j];
    }
    float win = pw[l + 1];
    #pragma unroll
    for (int j = 0; j < 32; ++j) acc[j] *= win;
    for (int m = 0; m <= l; ++m) {
        float a = 0.0f;
        #pragma unroll
        for (int d2 = 0; d2 < HD; ++d2) a += rs[l][d2] * ks[m][d2];
        a *= pw[l - m];
        #pragma unroll
        for (int j = 0; j < 32; ++j) acc[j] += a * vs[m][e0 + j];
    }
    size_t gg = (((size_t)(b * 1024 + n * CHUNK + l)) * HEADS + hh) * HD + e0;
    #pragma unroll
    for (int j = 0; j < 32; ++j) y[gg + j] = f2bf(acc[j]);
}

// ---------------- swiglu elementwise: g = silu(u1) * u2 ----------------
__global__ __launch_bounds__(256) void swiglu_mul(const unsigned short* __restrict__ u1,
                                                  const unsigned short* __restrict__ u2,
                                                  unsigned short* __restrict__ g) {
    size_t i = ((size_t)blockIdx.x * 256 + threadIdx.x) * 8;
    ushort4 a0 = *reinterpret_cast<const ushort4*>(u1 + i);
    ushort4 a1 = *reinterpret_cast<const ushort4*>(u1 + i + 4);
    ushort4 b0 = *reinterpret_cast<const ushort4*>(u2 + i);
    ushort4 b1 = *reinterpret_cast<const ushort4*>(u2 + i + 4);
    unsigned short au[8] = {a0.x, a0.y, a0.z, a0.w, a1.x, a1.y, a1.z, a1.w};
    unsigned short bu[8] = {b0.x, b0.y, b0.z, b0.w, b1.x, b1.y, b1.z, b1.w};
    unsigned short gu[8];
    #pragma unroll
    for (int j = 0; j < 8; ++j) {
        float a = bf2f(au[j]);
        float b = bf2f(bu[j]);
        float r = a / (1.0f + expf(-a)) * b;
        gu[j] = f2bf(r);
    }
    ushort4 g0; g0.x = gu[0]; g0.y = gu[1]; g0.z = gu[2]; g0.w = gu[3];
    ushort4 g1; g1.x = gu[4]; g1.y = gu[5]; g1.z = gu[6]; g1.w = gu[7];
    *reinterpret_cast<ushort4*>(g + i) = g0;
    *reinterpret_cast<ushort4*>(g + i + 4) = g1;
}

extern "C" void kernel_launch(void* const* d_in, const int* in_sizes, int n_in,
                              void* d_out, int out_size, void* d_ws, size_t ws_size,
                              hipStream_t stream) {
    const float* x      = (const float*)d_in[0];
    const float* norm1w = (const float*)d_in[1];
    const float* Wr     = (const float*)d_in[2];
    const float* Wk     = (const float*)d_in[3];
    const float* Wv     = (const float*)d_in[4];
    const float* Wo     = (const float*)d_in[5];
    const float* norm2w = (const float*)d_in[6];
    const float* w1     = (const float*)d_in[7];
    const float* w2     = (const float*)d_in[8];
    const float* w3     = (const float*)d_in[9];
    float* out = (float*)d_out;
    float* ws = (float*)d_ws;
    (void)in_sizes; (void)n_in; (void)out_size; (void)ws_size;

    const size_t MEG = 1048576;
    unsigned short* wr_t = (unsigned short*)(ws + 0);
    unsigned short* wv_t = (unsigned short*)(ws + MEG / 2);
    unsigned short* wo_t = (unsigned short*)(ws + MEG);
    unsigned short* w1_t = (unsigned short*)(ws + 3 * MEG / 2);
    unsigned short* w2_t = (unsigned short*)(ws + 7 * MEG / 2);
    unsigned short* w3_t = (unsigned short*)(ws + 11 * MEG / 2);
    float*          hbuf = ws + 15 * MEG / 2;                  // fp32 h (Wk path)
    unsigned short* h16  = (unsigned short*)(ws + 19 * MEG / 2);
    float*          rbuf = ws + 21 * MEG / 2;
    float*          kbuf = ws + 25 * MEG / 2;
    float*          vbuf = ws + 29 * MEG / 2;
    float*          Cbuf = ws + 33 * MEG / 2;
    float*          Sbuf = ws + 35 * MEG / 2;
    unsigned short* y16  = (unsigned short*)(ws + 37 * MEG / 2);
    // reuse (dead after attn_out / Wo-gemm):
    unsigned short* u1   = (unsigned short*)(ws + 21 * MEG / 2);  // over r
    unsigned short* u2   = (unsigned short*)(ws + 29 * MEG / 2);  // over v,C,S
    unsigned short* g16  = (unsigned short*)(ws + 37 * MEG / 2);  // over y16

    dim3 blk(256);

    // weight prep (every call; deterministic)
    transpose_cvt<<<dim3(32, 32),  blk, 0, stream>>>(Wr, wr_t, DIMD, DIMD);
    transpose_cvt<<<dim3(32, 32),  blk, 0, stream>>>(Wv, wv_t, DIMD, DIMD);
    transpose_cvt<<<dim3(32, 32),  blk, 0, stream>>>(Wo, wo_t, DIMD, DIMD);
    transpose_cvt<<<dim3(128, 32), blk, 0, stream>>>(w1, w1_t, DIMD, HIDDEN);
    transpose_cvt<<<dim3(128, 32), blk, 0, stream>>>(w2, w2_t, DIMD, HIDDEN);
    transpose_cvt<<<dim3(32, 128), blk, 0, stream>>>(w3, w3_t, HIDDEN, DIMD);

    // 1. h = rmsnorm(x, norm1) -> fp32 + bf16
    rmsnorm_kernel<<<BT, blk, 0, stream>>>(x, norm1w, hbuf, h16);
    // 2. r = sigmoid(h @ Wr)  (bf16 MFMA)
    gemm_bf16<1><<<dim3(DIMD / 128, BT / 128), blk, 0, stream>>>(h16, wr_t, rbuf, nullptr, BT, DIMD, DIMD);
    // 3. k = h @ Wk  (fp32 — kWTA-sensitive)
    gemm_f32<<<dim3(DIMD / 64, BT / 64), blk, 0, stream>>>(hbuf, Wk, kbuf, BT, DIMD, DIMD);
    // 4. spike + kWTA
    kwta_kernel<<<(BT * HEADS) / 4, blk, 0, stream>>>(kbuf, BT * HEADS);
    // 5. v = h @ Wv  (bf16 MFMA)
    gemm_bf16<0><<<dim3(DIMD / 128, BT / 128), blk, 0, stream>>>(h16, wv_t, vbuf, nullptr, BT, DIMD, DIMD);
    // 6-8. attention
    attn_state_kernel<<<NCHUNK * 32, blk, 0, stream>>>(kbuf, vbuf, Cbuf);
    attn_scan_kernel<<<32, blk, 0, stream>>>(Cbuf, Sbuf);
    attn_out_kernel<<<NCHUNK * 32, blk, 0, stream>>>(rbuf, kbuf, vbuf, Sbuf, y16);
    // 9. out = x + y @ Wo
    gemm_bf16<2><<<dim3(DIMD / 128, BT / 128), blk, 0, stream>>>(y16, wo_t, out, x, BT, DIMD, DIMD);
    // 10. h2 = rmsnorm(out, norm2) -> bf16 only
    rmsnorm_kernel<<<BT, blk, 0, stream>>>(out, norm2w, nullptr, h16);
    // 11. u1 = h2@w1, u2 = h2@w2, g = silu(u1)*u2
    gemm_bf16<3><<<dim3(HIDDEN / 128, BT / 128), blk, 0, stream>>>(h16, w1_t, u1, nullptr, BT, HIDDEN, DIMD);
    gemm_bf16<3><<<dim3(HIDDEN / 128, BT / 128), blk, 0, stream>>>(h16, w2_t, u2, nullptr, BT, HIDDEN, DIMD);
    swiglu_mul<<<(BT * HIDDEN) / (256 * 8), blk, 0, stream>>>(u1, u2, g16);
    // 12. out += g @ w3
    gemm_bf16<2><<<dim3(DIMD / 128, BT / 128), blk, 0, stream>>>(g16, w3_t, out, out, BT, DIMD, HIDDEN);
}

// Round 4
// 356.484 us; speedup vs baseline: 4.3866x; 1.2746x over previous
//
#include <hip/hip_runtime.h>
#include <hip/hip_bf16.h>
#include <math.h>

// AURA block. B=2, T=1024, D=1024, H=16, HD=64, chunk L=128, N=8, HIDDEN=4096.
// Round 4: fp32 Wk GEMM -> bf16x3 6-product MFMA (fp32-equivalent precision);
// MLP up-projections fused into one dual-B SwiGLU MFMA GEMM.

#define DIMD 1024
#define BT   2048
#define HEADS 16
#define HD   64
#define CHUNK 128
#define NCHUNK 8
#define HIDDEN 4096
#define DECAYF 0.9f
#define WL_128 1.3900845e-06f   // 0.9^128

typedef __attribute__((ext_vector_type(4))) float f32x4;
typedef __attribute__((ext_vector_type(8))) short bf16x8;

__device__ __forceinline__ unsigned short f2bf(float f) {
    __hip_bfloat16 h = __float2bfloat16(f);
    return __builtin_bit_cast(unsigned short, h);
}
__device__ __forceinline__ float bf2f(unsigned short u) {
    __hip_bfloat16 h = __builtin_bit_cast(__hip_bfloat16, u);
    return __bfloat162float(h);
}

__device__ __forceinline__ void gload_lds16(const void* g, void* l) {
    __builtin_amdgcn_global_load_lds(
        (const __attribute__((address_space(1))) void*)g,
        (__attribute__((address_space(3))) void*)l,
        16, 0, 0);
}

// ---------------- RMSNorm: bf16 out + optional bf16x3 split outputs ----------------
__global__ __launch_bounds__(256) void rmsnorm_kernel(const float* __restrict__ x,
                                                      const float* __restrict__ w,
                                                      unsigned short* __restrict__ h0,
                                                      unsigned short* __restrict__ h1,
                                                      unsigned short* __restrict__ h2) {
    int row = blockIdx.x;
    const float* xr = x + (size_t)row * DIMD;
    int i0 = threadIdx.x * 4;
    float4 v = *reinterpret_cast<const float4*>(xr + i0);
    float ss = v.x*v.x + v.y*v.y + v.z*v.z + v.w*v.w;
    #pragma unroll
    for (int off = 32; off; off >>= 1) ss += __shfl_xor(ss, off);
    __shared__ float red[4];
    if ((threadIdx.x & 63) == 0) red[threadIdx.x >> 6] = ss;
    __syncthreads();
    ss = red[0] + red[1] + red[2] + red[3];
    float norm = rsqrtf(ss * (1.0f / DIMD) + 1e-5f);
    float4 wv = *reinterpret_cast<const float4*>(w + i0);
    float o[4];
    o[0] = wv.x * v.x * norm; o[1] = wv.y * v.y * norm;
    o[2] = wv.z * v.z * norm; o[3] = wv.w * v.w * norm;
    ushort4 u0, u1, u2;
    unsigned short s0[4], s1[4], s2[4];
    #pragma unroll
    for (int j = 0; j < 4; ++j) {
        s0[j] = f2bf(o[j]);
        float r1 = o[j] - bf2f(s0[j]);
        s1[j] = f2bf(r1);
        float r2 = r1 - bf2f(s1[j]);
        s2[j] = f2bf(r2);
    }
    u0.x = s0[0]; u0.y = s0[1]; u0.z = s0[2]; u0.w = s0[3];
    *reinterpret_cast<ushort4*>(h0 + (size_t)row * DIMD + i0) = u0;
    if (h1) {
        u1.x = s1[0]; u1.y = s1[1]; u1.z = s1[2]; u1.w = s1[3];
        u2.x = s2[0]; u2.y = s2[1]; u2.z = s2[2]; u2.w = s2[3];
        *reinterpret_cast<ushort4*>(h1 + (size_t)row * DIMD + i0) = u1;
        *reinterpret_cast<ushort4*>(h2 + (size_t)row * DIMD + i0) = u2;
    }
}

// ---------------- transpose + fp32->bf16: dst[N][K] = src[K][N] ----------------
__global__ __launch_bounds__(256) void transpose_cvt(const float* __restrict__ src,
                                                     unsigned short* __restrict__ dst,
                                                     int K, int N) {
    __shared__ float t[32][33];
    int bn = blockIdx.x * 32, bk = blockIdx.y * 32;
    int tx = threadIdx.x & 31, ty = threadIdx.x >> 5;
    #pragma unroll
    for (int i = 0; i < 32; i += 8)
        t[ty + i][tx] = src[(size_t)(bk + ty + i) * N + bn + tx];
    __syncthreads();
    #pragma unroll
    for (int i = 0; i < 32; i += 8)
        dst[(size_t)(bn + ty + i) * K + bk + tx] = f2bf(t[tx][ty + i]);
}

// ---------------- transpose + bf16x3 split: dsti[N][K] = spliti(src[K][N]) ----------------
__global__ __launch_bounds__(256) void transpose_cvt3(const float* __restrict__ src,
                                                      unsigned short* __restrict__ d0,
                                                      unsigned short* __restrict__ d1,
                                                      unsigned short* __restrict__ d2,
                                                      int K, int N) {
    __shared__ float t[32][33];
    int bn = blockIdx.x * 32, bk = blockIdx.y * 32;
    int tx = threadIdx.x & 31, ty = threadIdx.x >> 5;
    #pragma unroll
    for (int i = 0; i < 32; i += 8)
        t[ty + i][tx] = src[(size_t)(bk + ty + i) * N + bn + tx];
    __syncthreads();
    #pragma unroll
    for (int i = 0; i < 32; i += 8) {
        float val = t[tx][ty + i];
        unsigned short b0 = f2bf(val);
        float r1 = val - bf2f(b0);
        unsigned short b1 = f2bf(r1);
        float r2 = r1 - bf2f(b1);
        unsigned short b2 = f2bf(r2);
        size_t o = (size_t)(bn + ty + i) * K + bk + tx;
        d0[o] = b0; d1[o] = b1; d2[o] = b2;
    }
}

// ---------------- bf16 MFMA GEMM: C[M,N] = A[M,K] @ Bt[N,K]^T ----------------
// EPI: 0 = fp32 out, 1 = sigmoid fp32 out, 2 = +add fp32 out, 3 = bf16 out
template <int EPI>
__global__ __launch_bounds__(256) void gemm_bf16(const unsigned short* __restrict__ A,
                                                 const unsigned short* __restrict__ Bt,
                                                 void* __restrict__ Cout,
                                                 const float* __restrict__ add,
                                                 int M, int N, int K) {
    __shared__ __align__(16) short As[128 * 64];
    __shared__ __align__(16) short Bs[128 * 64];
    const int tid = threadIdx.x;
    const int wv = tid >> 6, ln = tid & 63;
    const int bm = blockIdx.y << 7, bn = blockIdx.x << 7;
    const int wr = (wv >> 1) << 6, wc = (wv & 1) << 6;
    const int g = ln >> 4, r16 = ln & 15;

    f32x4 acc[4][4];
    #pragma unroll
    for (int i = 0; i < 4; ++i)
        #pragma unroll
        for (int j = 0; j < 4; ++j) acc[i][j] = (f32x4){0.f, 0.f, 0.f, 0.f};

    const short* Ag = (const short*)A;
    const short* Bg = (const short*)Bt;
    const int srow_off = ln >> 3;
    const int sslot = ln & 7;
    for (int k0 = 0; k0 < K; k0 += 64) {
        #pragma unroll
        for (int i = 0; i < 4; ++i) {
            int c = wv * 4 + i;
            int row = c * 8 + srow_off;
            int kcol = ((sslot ^ (row & 7)) << 3);
            gload_lds16(Ag + (size_t)(bm + row) * K + k0 + kcol, &As[c * 512 + ln * 8]);
            gload_lds16(Bg + (size_t)(bn + row) * K + k0 + kcol, &Bs[c * 512 + ln * 8]);
        }
        __syncthreads();
        #pragma unroll
        for (int kk = 0; kk < 2; ++kk) {
            bf16x8 af[4], bfr[4];
            #pragma unroll
            for (int mi = 0; mi < 4; ++mi) {
                int row = wr + mi * 16 + r16;
                int slot = (kk * 4 + g) ^ (row & 7);
                af[mi] = *reinterpret_cast<const bf16x8*>(&As[row * 64 + slot * 8]);
            }
            #pragma unroll
            for (int ni = 0; ni < 4; ++ni) {
                int row = wc + ni * 16 + r16;
                int slot = (kk * 4 + g) ^ (row & 7);
                bfr[ni] = *reinterpret_cast<const bf16x8*>(&Bs[row * 64 + slot * 8]);
            }
            #pragma unroll
            for (int mi = 0; mi < 4; ++mi)
                #pragma unroll
                for (int ni = 0; ni < 4; ++ni)
                    acc[mi][ni] = __builtin_amdgcn_mfma_f32_16x16x32_bf16(
                        af[mi], bfr[ni], acc[mi][ni], 0, 0, 0);
        }
        __syncthreads();
    }
    #pragma unroll
    for (int mi = 0; mi < 4; ++mi) {
        #pragma unroll
        for (int q = 0; q < 4; ++q) {
            int row = bm + wr + mi * 16 + g * 4 + q;
            #pragma unroll
            for (int ni = 0; ni < 4; ++ni) {
                int col = bn + wc + ni * 16 + r16;
                float vv = acc[mi][ni][q];
                size_t o = (size_t)row * N + col;
                if (EPI == 1) vv = 1.0f / (1.0f + expf(-vv));
                if (EPI == 2) vv += add[o];
                if (EPI == 3) ((unsigned short*)Cout)[o] = f2bf(vv);
                else          ((float*)Cout)[o] = vv;
            }
        }
    }
}

// ---------------- bf16x3 GEMM (fp32-equivalent): C = sum_{i+j<=2} Ai @ Bjt^T ----------------
// 64x64 tile, BK=64, 4 waves each 32x32.
__global__ __launch_bounds__(256) void gemm_k3(const unsigned short* __restrict__ A0,
                                               const unsigned short* __restrict__ A1,
                                               const unsigned short* __restrict__ A2,
                                               const unsigned short* __restrict__ B0,
                                               const unsigned short* __restrict__ B1,
                                               const unsigned short* __restrict__ B2,
                                               float* __restrict__ C,
                                               int M, int N, int K) {
    __shared__ __align__(16) short As[3][64 * 64];
    __shared__ __align__(16) short Bs[3][64 * 64];
    const int tid = threadIdx.x;
    const int wv = tid >> 6, ln = tid & 63;
    const int bm = blockIdx.y << 6, bn = blockIdx.x << 6;
    const int wr = (wv >> 1) << 5, wc = (wv & 1) << 5;
    const int g = ln >> 4, r16 = ln & 15;

    f32x4 acc[2][2];
    #pragma unroll
    for (int i = 0; i < 2; ++i)
        #pragma unroll
        for (int j = 0; j < 2; ++j) acc[i][j] = (f32x4){0.f, 0.f, 0.f, 0.f};

    const short* Ag[3] = {(const short*)A0, (const short*)A1, (const short*)A2};
    const short* Bg[3] = {(const short*)B0, (const short*)B1, (const short*)B2};
    const int PA[6] = {0, 0, 1, 1, 0, 2};
    const int PB[6] = {0, 1, 0, 1, 2, 0};

    const int srow_off = ln >> 3;
    const int sslot = ln & 7;
    for (int k0 = 0; k0 < K; k0 += 64) {
        #pragma unroll
        for (int p = 0; p < 3; ++p) {
            #pragma unroll
            for (int i = 0; i < 2; ++i) {
                int c = wv * 2 + i;
                int row = c * 8 + srow_off;
                int kcol = ((sslot ^ (row & 7)) << 3);
                gload_lds16(Ag[p] + (size_t)(bm + row) * K + k0 + kcol, &As[p][c * 512 + ln * 8]);
                gload_lds16(Bg[p] + (size_t)(bn + row) * K + k0 + kcol, &Bs[p][c * 512 + ln * 8]);
            }
        }
        __syncthreads();
        #pragma unroll
        for (int kk = 0; kk < 2; ++kk) {
            bf16x8 af[3][2], bfr[3][2];
            #pragma unroll
            for (int p = 0; p < 3; ++p) {
                #pragma unroll
                for (int mi = 0; mi < 2; ++mi) {
                    int row = wr + mi * 16 + r16;
                    int slot = (kk * 4 + g) ^ (row & 7);
                    af[p][mi] = *reinterpret_cast<const bf16x8*>(&As[p][row * 64 + slot * 8]);
                }
                #pragma unroll
                for (int ni = 0; ni < 2; ++ni) {
                    int row = wc + ni * 16 + r16;
                    int slot = (kk * 4 + g) ^ (row & 7);
                    bfr[p][ni] = *reinterpret_cast<const bf16x8*>(&Bs[p][row * 64 + slot * 8]);
                }
            }
            #pragma unroll
            for (int pp = 0; pp < 6; ++pp) {
                #pragma unroll
                for (int mi = 0; mi < 2; ++mi)
                    #pragma unroll
                    for (int ni = 0; ni < 2; ++ni)
                        acc[mi][ni] = __builtin_amdgcn_mfma_f32_16x16x32_bf16(
                            af[PA[pp]][mi], bfr[PB[pp]][ni], acc[mi][ni], 0, 0, 0);
            }
        }
        __syncthreads();
    }
    #pragma unroll
    for (int mi = 0; mi < 2; ++mi)
        #pragma unroll
        for (int q = 0; q < 4; ++q) {
            int row = bm + wr + mi * 16 + g * 4 + q;
            #pragma unroll
            for (int ni = 0; ni < 2; ++ni) {
                int col = bn + wc + ni * 16 + r16;
                C[(size_t)row * N + col] = acc[mi][ni][q];
            }
        }
}

// ---------------- dual-B SwiGLU GEMM: g = silu(A@B1^T) * (A@B2^T), bf16 out ----------------
// 128x64 tile, BK=64, 4 waves each 64x32.
__global__ __launch_bounds__(256) void gemm_swiglu_bf16(const unsigned short* __restrict__ A,
                                                        const unsigned short* __restrict__ B1t,
                                                        const unsigned short* __restrict__ B2t,
                                                        unsigned short* __restrict__ G,
                                                        int M, int N, int K) {
    __shared__ __align__(16) short As[128 * 64];
    __shared__ __align__(16) short Bs1[64 * 64];
    __shared__ __align__(16) short Bs2[64 * 64];
    const int tid = threadIdx.x;
    const int wv = tid >> 6, ln = tid & 63;
    const int bm = blockIdx.y << 7, bn = blockIdx.x << 6;
    const int wr = (wv >> 1) << 6, wc = (wv & 1) << 5;
    const int g = ln >> 4, r16 = ln & 15;

    f32x4 acc1[4][2], acc2[4][2];
    #pragma unroll
    for (int i = 0; i < 4; ++i)
        #pragma unroll
        for (int j = 0; j < 2; ++j) {
            acc1[i][j] = (f32x4){0.f, 0.f, 0.f, 0.f};
            acc2[i][j] = (f32x4){0.f, 0.f, 0.f, 0.f};
        }

    const short* Ag = (const short*)A;
    const short* B1g = (const short*)B1t;
    const short* B2g = (const short*)B2t;
    const int srow_off = ln >> 3;
    const int sslot = ln & 7;
    for (int k0 = 0; k0 < K; k0 += 64) {
        #pragma unroll
        for (int i = 0; i < 4; ++i) {
            int c = wv * 4 + i;
            int row = c * 8 + srow_off;
            int kcol = ((sslot ^ (row & 7)) << 3);
            gload_lds16(Ag + (size_t)(bm + row) * K + k0 + kcol, &As[c * 512 + ln * 8]);
        }
        {
            int c = wv * 2;
            int row0 = c * 8 + srow_off;
            int kcol0 = ((sslot ^ (row0 & 7)) << 3);
            gload_lds16(B1g + (size_t)(bn + row0) * K + k0 + kcol0, &Bs1[c * 512 + ln * 8]);
            gload_lds16(B2g + (size_t)(bn + row0) * K + k0 + kcol0, &Bs2[c * 512 + ln * 8]);
            int c1 = c + 1;
            int row1 = c1 * 8 + srow_off;
            int kcol1 = ((sslot ^ (row1 & 7)) << 3);
            gload_lds16(B1g + (size_t)(bn + row1) * K + k0 + kcol1, &Bs1[c1 * 512 + ln * 8]);
            gload_lds16(B2g + (size_t)(bn + row1) * K + k0 + kcol1, &Bs2[c1 * 512 + ln * 8]);
        }
        __syncthreads();
        #pragma unroll
        for (int kk = 0; kk < 2; ++kk) {
            bf16x8 af[4], b1f[2], b2f[2];
            #pragma unroll
            for (int mi = 0; mi < 4; ++mi) {
                int row = wr + mi * 16 + r16;
                int slot = (kk * 4 + g) ^ (row & 7);
                af[mi] = *reinterpret_cast<const bf16x8*>(&As[row * 64 + slot * 8]);
            }
            #pragma unroll
            for (int ni = 0; ni < 2; ++ni) {
                int row = wc + ni * 16 + r16;
                int slot = (kk * 4 + g) ^ (row & 7);
                b1f[ni] = *reinterpret_cast<const bf16x8*>(&Bs1[row * 64 + slot * 8]);
                b2f[ni] = *reinterpret_cast<const bf16x8*>(&Bs2[row * 64 + slot * 8]);
            }
            #pragma unroll
            for (int mi = 0; mi < 4; ++mi)
                #pragma unroll
                for (int ni = 0; ni < 2; ++ni) {
                    acc1[mi][ni] = __builtin_amdgcn_mfma_f32_16x16x32_bf16(
                        af[mi], b1f[ni], acc1[mi][ni], 0, 0, 0);
                    acc2[mi][ni] = __builtin_amdgcn_mfma_f32_16x16x32_bf16(
                        af[mi], b2f[ni], acc2[mi][ni], 0, 0, 0);
                }
        }
        __syncthreads();
    }
    #pragma unroll
    for (int mi = 0; mi < 4; ++mi)
        #pragma unroll
        for (int q = 0; q < 4; ++q) {
            int row = bm + wr + mi * 16 + g * 4 + q;
            #pragma unroll
            for (int ni = 0; ni < 2; ++ni) {
                int col = bn + wc + ni * 16 + r16;
                float a = acc1[mi][ni][q];
                float vv = a / (1.0f + expf(-a)) * acc2[mi][ni][q];
                G[(size_t)row * N + col] = f2bf(vv);
            }
        }
}

// ---------------- spike threshold + k-winners-take-all ----------------
__global__ __launch_bounds__(256) void kwta_kernel(float* __restrict__ k, int total) {
    int wid = (int)((blockIdx.x * (size_t)blockDim.x + threadIdx.x) >> 6);
    int lane = threadIdx.x & 63;
    if (wid >= total) return;
    float* base = k + (size_t)wid * HD;
    float v = base[lane];
    float val = (v > 0.5f) ? v : 0.0f;
    float cur = val;
    float thr = 0.0f;
    #pragma unroll
    for (int it = 0; it < 4; ++it) {
        float m = cur;
        #pragma unroll
        for (int off = 32; off; off >>= 1) m = fmaxf(m, __shfl_xor(m, off));
        thr = m;
        unsigned long long ball = __ballot(cur == m);
        int leader = __ffsll((unsigned long long)ball) - 1;
        if (lane == leader) cur = -1.0f;
    }
    base[lane] = (val >= thr) ? val : 0.0f;
}

// ---------------- attention pass A ----------------
__global__ __launch_bounds__(256) void attn_state_kernel(const float* __restrict__ k,
                                                         const float* __restrict__ v,
                                                         float* __restrict__ Cbuf) {
    int n = blockIdx.x >> 5;
    int bh = blockIdx.x & 31;
    int b = bh >> 4, hh = bh & 15;
    __shared__ float ks[CHUNK][HD + 1];
    __shared__ float vs[CHUNK][HD + 1];
    __shared__ float pw[CHUNK + 1];
    int tid = threadIdx.x;
    if (tid < CHUNK + 1) pw[tid] = powf(DECAYF, (float)tid);
    __syncthreads();
    #pragma unroll
    for (int i = 0; i < 32; ++i) {
        int idx = tid + (i << 8);
        int l = idx >> 6, d = idx & 63;
        size_t gg = (((size_t)(b * 1024 + n * CHUNK + l)) * HEADS + hh) * HD + d;
        ks[l][d] = k[gg] * pw[CHUNK - 1 - l];
        vs[l][d] = v[gg];
    }
    __syncthreads();
    int d = tid >> 2;
    int e0 = (tid & 3) << 4;
    float acc[16] = {};
    for (int l = 0; l < CHUNK; ++l) {
        float kv = ks[l][d];
        #pragma unroll
        for (int j = 0; j < 16; ++j) acc[j] += kv * vs[l][e0 + j];
    }
    size_t off = (size_t)blockIdx.x * 4096 + d * 64 + e0;
    #pragma unroll
    for (int j = 0; j < 16; ++j) Cbuf[off + j] = acc[j];
}

// ---------------- attention pass B ----------------
__global__ __launch_bounds__(256) void attn_scan_kernel(const float* __restrict__ Cbuf,
                                                        float* __restrict__ Sbuf) {
    int bh = blockIdx.x;
    int tid = threadIdx.x;
    float S[16];
    #pragma unroll
    for (int j = 0; j < 16; ++j) S[j] = 0.0f;
    for (int n = 0; n < NCHUNK; ++n) {
        size_t off = ((size_t)(n * 32 + bh)) * 4096 + tid * 16;
        #pragma unroll
        for (int j = 0; j < 16; ++j) Sbuf[off + j] = S[j];
        #pragma unroll
        for (int j = 0; j < 16; ++j) S[j] = WL_128 * S[j] + Cbuf[off + j];
    }
}

// ---------------- attention pass C ----------------
__global__ __launch_bounds__(256) void attn_out_kernel(const float* __restrict__ r,
                                                       const float* __restrict__ k,
                                                       const float* __restrict__ v,
                                                       const float* __restrict__ Sbuf,
                                                       unsigned short* __restrict__ y) {
    int n = blockIdx.x >> 5;
    int bh = blockIdx.x & 31;
    int b = bh >> 4, hh = bh & 15;
    __shared__ float rs[CHUNK][HD + 1];
    __shared__ float ks[CHUNK][HD + 1];
    __shared__ float vs[CHUNK][HD + 1];
    __shared__ float Ss[HD][HD + 1];
    __shared__ float pw[CHUNK + 1];
    int tid = threadIdx.x;
    if (tid < CHUNK + 1) pw[tid] = powf(DECAYF, (float)tid);
    #pragma unroll
    for (int i = 0; i < 32; ++i) {
        int idx = tid + (i << 8);
        int l = idx >> 6, d = idx & 63;
        size_t gg = (((size_t)(b * 1024 + n * CHUNK + l)) * HEADS + hh) * HD + d;
        rs[l][d] = r[gg];
        ks[l][d] = k[gg];
        vs[l][d] = v[gg];
    }
    {
        size_t soff = (size_t)blockIdx.x * 4096;
        #pragma unroll
        for (int i = 0; i < 16; ++i) {
            int idx = tid + (i << 8);
            Ss[idx >> 6][idx & 63] = Sbuf[soff + idx];
        }
    }
    __syncthreads();
    int l = tid >> 1;
    int e0 = (tid & 1) << 5;
    float acc[32] = {};
    for (int d2 = 0; d2 < HD; ++d2) {
        float rv = rs[l][d2];
        #pragma unroll
        for (int j = 0; j < 32; ++j) acc[j] += rv * Ss[d2][e0 + j];
    }
    float win = pw[l + 1];
    #pragma unroll
    for (int j = 0; j < 32; ++j) acc[j] *= win;
    for (int m = 0; m <= l; ++m) {
        float a = 0.0f;
        #pragma unroll
        for (int d2 = 0; d2 < HD; ++d2) a += rs[l][d2] * ks[m][d2];
        a *= pw[l - m];
        #pragma unroll
        for (int j = 0; j < 32; ++j) acc[j] += a * vs[m][e0 + j];
    }
    size_t gg = (((size_t)(b * 1024 + n * CHUNK + l)) * HEADS + hh) * HD + e0;
    #pragma unroll
    for (int j = 0; j < 32; ++j) y[gg + j] = f2bf(acc[j]);
}

extern "C" void kernel_launch(void* const* d_in, const int* in_sizes, int n_in,
                              void* d_out, int out_size, void* d_ws, size_t ws_size,
                              hipStream_t stream) {
    const float* x      = (const float*)d_in[0];
    const float* norm1w = (const float*)d_in[1];
    const float* Wr     = (const float*)d_in[2];
    const float* Wk     = (const float*)d_in[3];
    const float* Wv     = (const float*)d_in[4];
    const float* Wo     = (const float*)d_in[5];
    const float* norm2w = (const float*)d_in[6];
    const float* w1     = (const float*)d_in[7];
    const float* w2     = (const float*)d_in[8];
    const float* w3     = (const float*)d_in[9];
    float* out = (float*)d_out;
    char* ws = (char*)d_ws;
    (void)in_sizes; (void)n_in; (void)out_size; (void)ws_size;

    const size_t MB = 1048576;
    unsigned short* wr_t = (unsigned short*)(ws + 0 * MB);    // 2 MB
    unsigned short* wv_t = (unsigned short*)(ws + 2 * MB);    // 2 MB
    unsigned short* wo_t = (unsigned short*)(ws + 4 * MB);    // 2 MB
    unsigned short* w1_t = (unsigned short*)(ws + 6 * MB);    // 8 MB
    unsigned short* w2_t = (unsigned short*)(ws + 14 * MB);   // 8 MB
    unsigned short* w3_t = (unsigned short*)(ws + 22 * MB);   // 8 MB
    unsigned short* wk0  = (unsigned short*)(ws + 30 * MB);   // 2 MB
    unsigned short* wk1  = (unsigned short*)(ws + 32 * MB);   // 2 MB
    unsigned short* wk2  = (unsigned short*)(ws + 34 * MB);   // 2 MB
    unsigned short* h0   = (unsigned short*)(ws + 36 * MB);   // 4 MB
    unsigned short* h1   = (unsigned short*)(ws + 40 * MB);   // 4 MB
    unsigned short* h2   = (unsigned short*)(ws + 44 * MB);   // 4 MB
    float*          rbuf = (float*)(ws + 48 * MB);            // 8 MB
    float*          kbuf = (float*)(ws + 56 * MB);            // 8 MB
    float*          vbuf = (float*)(ws + 64 * MB);            // 8 MB
    float*          Cbuf = (float*)(ws + 40 * MB);            // 4 MB (over h1, dead post-k3)
    float*          Sbuf = (float*)(ws + 44 * MB);            // 4 MB (over h2, dead post-k3)
    unsigned short* y16  = (unsigned short*)(ws + 72 * MB);   // 4 MB  (peak: 76 MB)
    // MLP phase (everything above 30 MB dead after Wo GEMM):
    unsigned short* h0b  = (unsigned short*)(ws + 30 * MB);   // 4 MB
    unsigned short* g16  = (unsigned short*)(ws + 34 * MB);   // 16 MB (ends 50 MB)

    dim3 blk(256);

    transpose_cvt<<<dim3(32, 32),  blk, 0, stream>>>(Wr, wr_t, DIMD, DIMD);
    transpose_cvt<<<dim3(32, 32),  blk, 0, stream>>>(Wv, wv_t, DIMD, DIMD);
    transpose_cvt<<<dim3(32, 32),  blk, 0, stream>>>(Wo, wo_t, DIMD, DIMD);
    transpose_cvt<<<dim3(128, 32), blk, 0, stream>>>(w1, w1_t, DIMD, HIDDEN);
    transpose_cvt<<<dim3(128, 32), blk, 0, stream>>>(w2, w2_t, DIMD, HIDDEN);
    transpose_cvt<<<dim3(32, 128), blk, 0, stream>>>(w3, w3_t, HIDDEN, DIMD);
    transpose_cvt3<<<dim3(32, 32), blk, 0, stream>>>(Wk, wk0, wk1, wk2, DIMD, DIMD);

    // 1. h = rmsnorm(x, norm1) -> bf16x3 splits
    rmsnorm_kernel<<<BT, blk, 0, stream>>>(x, norm1w, h0, h1, h2);
    // 2. r = sigmoid(h @ Wr)
    gemm_bf16<1><<<dim3(DIMD / 128, BT / 128), blk, 0, stream>>>(h0, wr_t, rbuf, nullptr, BT, DIMD, DIMD);
    // 3. k = h @ Wk  (bf16x3 6-product, fp32-equivalent)
    gemm_k3<<<dim3(DIMD / 64, BT / 64), blk, 0, stream>>>(h0, h1, h2, wk0, wk1, wk2, kbuf, BT, DIMD, DIMD);
    // 4. spike + kWTA
    kwta_kernel<<<(BT * HEADS) / 4, blk, 0, stream>>>(kbuf, BT * HEADS);
    // 5. v = h @ Wv
    gemm_bf16<0><<<dim3(DIMD / 128, BT / 128), blk, 0, stream>>>(h0, wv_t, vbuf, nullptr, BT, DIMD, DIMD);
    // 6-8. attention
    attn_state_kernel<<<NCHUNK * 32, blk, 0, stream>>>(kbuf, vbuf, Cbuf);
    attn_scan_kernel<<<32, blk, 0, stream>>>(Cbuf, Sbuf);
    attn_out_kernel<<<NCHUNK * 32, blk, 0, stream>>>(rbuf, kbuf, vbuf, Sbuf, y16);
    // 9. out = x + y @ Wo
    gemm_bf16<2><<<dim3(DIMD / 128, BT / 128), blk, 0, stream>>>(y16, wo_t, out, x, BT, DIMD, DIMD);
    // 10. h2n = rmsnorm(out, norm2) -> bf16 only
    rmsnorm_kernel<<<BT, blk, 0, stream>>>(out, norm2w, h0b, nullptr, nullptr);
    // 11. g = silu(h@w1) * (h@w2)  (dual-B fused)
    gemm_swiglu_bf16<<<dim3(HIDDEN / 64, BT / 128), blk, 0, stream>>>(h0b, w1_t, w2_t, g16, BT, HIDDEN, DIMD);
    // 12. out += g @ w3
    gemm_bf16<2><<<dim3(DIMD / 128, BT / 128), blk, 0, stream>>>(g16, w3_t, out, out, BT, DIMD, HIDDEN);
}

// Round 5
// 265.585 us; speedup vs baseline: 5.8880x; 1.3423x over previous
//
#include <hip/hip_runtime.h>
#include <hip/hip_bf16.h>
#include <math.h>

// AURA block. B=2, T=1024, D=1024, H=16, HD=64, chunk L=128, N=8, HIDDEN=4096.
// Round 5: full-MFMA attention (transposed-operand pipeline), split-K w3,
// vectorized transposes, 128^2 swiglu tile.

#define DIMD 1024
#define BT   2048
#define HEADS 16
#define HD   64
#define CHUNK 128
#define NCHUNK 8
#define HIDDEN 4096
#define WL_128 1.3900845e-06f           // 0.9^128
#define LOG2D  (-0.15200309344504997f)  // log2(0.9)

typedef __attribute__((ext_vector_type(4))) float f32x4;
typedef __attribute__((ext_vector_type(8))) short bf16x8;

__device__ __forceinline__ unsigned short f2bf(float f) {
    __hip_bfloat16 h = __float2bfloat16(f);
    return __builtin_bit_cast(unsigned short, h);
}
__device__ __forceinline__ float bf2f(unsigned short u) {
    __hip_bfloat16 h = __builtin_bit_cast(__hip_bfloat16, u);
    return __bfloat162float(h);
}
__device__ __forceinline__ void gload_lds16(const void* g, void* l) {
    __builtin_amdgcn_global_load_lds(
        (const __attribute__((address_space(1))) void*)g,
        (__attribute__((address_space(3))) void*)l,
        16, 0, 0);
}

// ---------------- RMSNorm: bf16 out (+ optional bf16x3 split outputs) ----------------
__global__ __launch_bounds__(256) void rmsnorm_kernel(const float* __restrict__ x,
                                                      const float* __restrict__ w,
                                                      unsigned short* __restrict__ h0,
                                                      unsigned short* __restrict__ h1,
                                                      unsigned short* __restrict__ h2) {
    int row = blockIdx.x;
    const float* xr = x + (size_t)row * DIMD;
    int i0 = threadIdx.x * 4;
    float4 v = *reinterpret_cast<const float4*>(xr + i0);
    float ss = v.x*v.x + v.y*v.y + v.z*v.z + v.w*v.w;
    #pragma unroll
    for (int off = 32; off; off >>= 1) ss += __shfl_xor(ss, off);
    __shared__ float red[4];
    if ((threadIdx.x & 63) == 0) red[threadIdx.x >> 6] = ss;
    __syncthreads();
    ss = red[0] + red[1] + red[2] + red[3];
    float norm = rsqrtf(ss * (1.0f / DIMD) + 1e-5f);
    float4 wv = *reinterpret_cast<const float4*>(w + i0);
    float o[4];
    o[0] = wv.x * v.x * norm; o[1] = wv.y * v.y * norm;
    o[2] = wv.z * v.z * norm; o[3] = wv.w * v.w * norm;
    ushort4 u0;
    unsigned short s0[4], s1[4], s2[4];
    #pragma unroll
    for (int j = 0; j < 4; ++j) {
        s0[j] = f2bf(o[j]);
        float r1 = o[j] - bf2f(s0[j]);
        s1[j] = f2bf(r1);
        float r2 = r1 - bf2f(s1[j]);
        s2[j] = f2bf(r2);
    }
    u0.x = s0[0]; u0.y = s0[1]; u0.z = s0[2]; u0.w = s0[3];
    *reinterpret_cast<ushort4*>(h0 + (size_t)row * DIMD + i0) = u0;
    if (h1) {
        ushort4 u1, u2;
        u1.x = s1[0]; u1.y = s1[1]; u1.z = s1[2]; u1.w = s1[3];
        u2.x = s2[0]; u2.y = s2[1]; u2.z = s2[2]; u2.w = s2[3];
        *reinterpret_cast<ushort4*>(h1 + (size_t)row * DIMD + i0) = u1;
        *reinterpret_cast<ushort4*>(h2 + (size_t)row * DIMD + i0) = u2;
    }
}

// ---------------- fast transpose + cvt: dst[N][K] = bf16(src[K][N]) ----------------
__global__ __launch_bounds__(256) void transpose_w(const float* __restrict__ src,
                                                   unsigned short* __restrict__ dst,
                                                   int K, int N) {
    __shared__ float t[64][65];
    int bn = blockIdx.x * 64, bk = blockIdx.y * 64;
    int tx = threadIdx.x & 15, ty = threadIdx.x >> 4;
    #pragma unroll
    for (int i = 0; i < 4; ++i) {
        float4 v = *reinterpret_cast<const float4*>(&src[(size_t)(bk + ty + i * 16) * N + bn + tx * 4]);
        t[ty + i * 16][tx * 4 + 0] = v.x;
        t[ty + i * 16][tx * 4 + 1] = v.y;
        t[ty + i * 16][tx * 4 + 2] = v.z;
        t[ty + i * 16][tx * 4 + 3] = v.w;
    }
    __syncthreads();
    #pragma unroll
    for (int i = 0; i < 4; ++i) {
        int nrow = ty + i * 16;
        ushort4 o;
        o.x = f2bf(t[tx * 4 + 0][nrow]);
        o.y = f2bf(t[tx * 4 + 1][nrow]);
        o.z = f2bf(t[tx * 4 + 2][nrow]);
        o.w = f2bf(t[tx * 4 + 3][nrow]);
        *reinterpret_cast<ushort4*>(&dst[(size_t)(bn + nrow) * K + bk + tx * 4]) = o;
    }
}

// ---------------- transpose + bf16x3 split (Wk) ----------------
__global__ __launch_bounds__(256) void transpose_cvt3(const float* __restrict__ src,
                                                      unsigned short* __restrict__ d0,
                                                      unsigned short* __restrict__ d1,
                                                      unsigned short* __restrict__ d2,
                                                      int K, int N) {
    __shared__ float t[64][65];
    int bn = blockIdx.x * 64, bk = blockIdx.y * 64;
    int tx = threadIdx.x & 15, ty = threadIdx.x >> 4;
    #pragma unroll
    for (int i = 0; i < 4; ++i) {
        float4 v = *reinterpret_cast<const float4*>(&src[(size_t)(bk + ty + i * 16) * N + bn + tx * 4]);
        t[ty + i * 16][tx * 4 + 0] = v.x;
        t[ty + i * 16][tx * 4 + 1] = v.y;
        t[ty + i * 16][tx * 4 + 2] = v.z;
        t[ty + i * 16][tx * 4 + 3] = v.w;
    }
    __syncthreads();
    #pragma unroll
    for (int i = 0; i < 4; ++i) {
        int nrow = ty + i * 16;
        ushort4 o0, o1, o2;
        unsigned short* p0 = (unsigned short*)&o0;
        unsigned short* p1 = (unsigned short*)&o1;
        unsigned short* p2 = (unsigned short*)&o2;
        #pragma unroll
        for (int j = 0; j < 4; ++j) {
            float val = t[tx * 4 + j][nrow];
            unsigned short b0 = f2bf(val);
            float r1 = val - bf2f(b0);
            unsigned short b1 = f2bf(r1);
            float r2 = r1 - bf2f(b1);
            p0[j] = b0; p1[j] = b1; p2[j] = f2bf(r2);
        }
        size_t oo = (size_t)(bn + nrow) * K + bk + tx * 4;
        *reinterpret_cast<ushort4*>(&d0[oo]) = o0;
        *reinterpret_cast<ushort4*>(&d1[oo]) = o1;
        *reinterpret_cast<ushort4*>(&d2[oo]) = o2;
    }
}

// ---------------- bf16 per-batch transpose for attention operands ----------------
// dst[b*1024 + c][t] = src[b*1024 + t][c] * (scaled ? decay^(127-(t&127)) : 1)
__global__ __launch_bounds__(256) void transpose_attn(const unsigned short* __restrict__ src,
                                                      unsigned short* __restrict__ dst,
                                                      int scaled) {
    __shared__ float t[64][65];
    int bc = blockIdx.x * 64, bt = blockIdx.y * 64, b = blockIdx.z;
    int tx = threadIdx.x & 15, ty = threadIdx.x >> 4;
    #pragma unroll
    for (int i = 0; i < 4; ++i) {
        ushort4 v = *reinterpret_cast<const ushort4*>(&src[(size_t)(b * 1024 + bt + ty + i * 16) * 1024 + bc + tx * 4]);
        t[ty + i * 16][tx * 4 + 0] = bf2f(v.x);
        t[ty + i * 16][tx * 4 + 1] = bf2f(v.y);
        t[ty + i * 16][tx * 4 + 2] = bf2f(v.z);
        t[ty + i * 16][tx * 4 + 3] = bf2f(v.w);
    }
    __syncthreads();
    #pragma unroll
    for (int i = 0; i < 4; ++i) {
        int crow = ty + i * 16;
        ushort4 o;
        unsigned short* po = (unsigned short*)&o;
        #pragma unroll
        for (int j = 0; j < 4; ++j) {
            int tl = bt + tx * 4 + j;
            float sc = scaled ? exp2f((float)(127 - (tl & 127)) * LOG2D) : 1.0f;
            po[j] = f2bf(t[tx * 4 + j][crow] * sc);
        }
        *reinterpret_cast<ushort4*>(&dst[(size_t)(b * 1024 + bc + crow) * 1024 + bt + tx * 4]) = o;
    }
}

// ---------------- bf16 MFMA GEMM: C[M,N] = A[M,K] @ Bt[N,K]^T ----------------
// EPI: 0 fp32, 2 +add fp32, 3 bf16, 4 sigmoid bf16
template <int EPI>
__global__ __launch_bounds__(256) void gemm_bf16(const unsigned short* __restrict__ A,
                                                 const unsigned short* __restrict__ Bt,
                                                 void* __restrict__ Cout,
                                                 const float* __restrict__ add,
                                                 int M, int N, int K) {
    __shared__ __align__(16) short As[128 * 64];
    __shared__ __align__(16) short Bs[128 * 64];
    const int tid = threadIdx.x;
    const int wv = tid >> 6, ln = tid & 63;
    const int bm = blockIdx.y << 7, bn = blockIdx.x << 7;
    const int wr = (wv >> 1) << 6, wc = (wv & 1) << 6;
    const int g = ln >> 4, r16 = ln & 15;

    f32x4 acc[4][4];
    #pragma unroll
    for (int i = 0; i < 4; ++i)
        #pragma unroll
        for (int j = 0; j < 4; ++j) acc[i][j] = (f32x4){0.f, 0.f, 0.f, 0.f};

    const short* Ag = (const short*)A;
    const short* Bg = (const short*)Bt;
    const int srow_off = ln >> 3;
    const int sslot = ln & 7;
    for (int k0 = 0; k0 < K; k0 += 64) {
        #pragma unroll
        for (int i = 0; i < 4; ++i) {
            int c = wv * 4 + i;
            int row = c * 8 + srow_off;
            int kcol = ((sslot ^ (row & 7)) << 3);
            gload_lds16(Ag + (size_t)(bm + row) * K + k0 + kcol, &As[c * 512 + ln * 8]);
            gload_lds16(Bg + (size_t)(bn + row) * K + k0 + kcol, &Bs[c * 512 + ln * 8]);
        }
        __syncthreads();
        #pragma unroll
        for (int kk = 0; kk < 2; ++kk) {
            bf16x8 af[4], bfr[4];
            #pragma unroll
            for (int mi = 0; mi < 4; ++mi) {
                int row = wr + mi * 16 + r16;
                int slot = (kk * 4 + g) ^ (row & 7);
                af[mi] = *reinterpret_cast<const bf16x8*>(&As[row * 64 + slot * 8]);
            }
            #pragma unroll
            for (int ni = 0; ni < 4; ++ni) {
                int row = wc + ni * 16 + r16;
                int slot = (kk * 4 + g) ^ (row & 7);
                bfr[ni] = *reinterpret_cast<const bf16x8*>(&Bs[row * 64 + slot * 8]);
            }
            #pragma unroll
            for (int mi = 0; mi < 4; ++mi)
                #pragma unroll
                for (int ni = 0; ni < 4; ++ni)
                    acc[mi][ni] = __builtin_amdgcn_mfma_f32_16x16x32_bf16(
                        af[mi], bfr[ni], acc[mi][ni], 0, 0, 0);
        }
        __syncthreads();
    }
    #pragma unroll
    for (int mi = 0; mi < 4; ++mi) {
        #pragma unroll
        for (int q = 0; q < 4; ++q) {
            int row = bm + wr + mi * 16 + g * 4 + q;
            #pragma unroll
            for (int ni = 0; ni < 4; ++ni) {
                int col = bn + wc + ni * 16 + r16;
                float vv = acc[mi][ni][q];
                size_t o = (size_t)row * N + col;
                if (EPI == 2) vv += add[o];
                if (EPI == 4) vv = 1.0f / (1.0f + expf(-vv));
                if (EPI == 3 || EPI == 4) ((unsigned short*)Cout)[o] = f2bf(vv);
                else                      ((float*)Cout)[o] = vv;
            }
        }
    }
}

// ---------------- split-K GEMM (w3): partial[z] = A[:, z*1024:+1024] @ B^T ----------------
__global__ __launch_bounds__(256) void gemm_splitk(const unsigned short* __restrict__ A,
                                                   const unsigned short* __restrict__ Bt,
                                                   float* __restrict__ P01,
                                                   float* __restrict__ P23,
                                                   int M, int N, int lda) {
    __shared__ __align__(16) short As[128 * 64];
    __shared__ __align__(16) short Bs[128 * 64];
    const int tid = threadIdx.x;
    const int wv = tid >> 6, ln = tid & 63;
    const int bm = blockIdx.y << 7, bn = blockIdx.x << 7;
    const int z = blockIdx.z;
    const int wr = (wv >> 1) << 6, wc = (wv & 1) << 6;
    const int g = ln >> 4, r16 = ln & 15;
    float* C = (z < 2) ? (P01 + (size_t)z * M * N) : (P23 + (size_t)(z - 2) * M * N);

    f32x4 acc[4][4];
    #pragma unroll
    for (int i = 0; i < 4; ++i)
        #pragma unroll
        for (int j = 0; j < 4; ++j) acc[i][j] = (f32x4){0.f, 0.f, 0.f, 0.f};

    const short* Ag = (const short*)A + z * 1024;
    const short* Bg = (const short*)Bt + z * 1024;
    const int srow_off = ln >> 3;
    const int sslot = ln & 7;
    for (int k0 = 0; k0 < 1024; k0 += 64) {
        #pragma unroll
        for (int i = 0; i < 4; ++i) {
            int c = wv * 4 + i;
            int row = c * 8 + srow_off;
            int kcol = ((sslot ^ (row & 7)) << 3);
            gload_lds16(Ag + (size_t)(bm + row) * lda + k0 + kcol, &As[c * 512 + ln * 8]);
            gload_lds16(Bg + (size_t)(bn + row) * lda + k0 + kcol, &Bs[c * 512 + ln * 8]);
        }
        __syncthreads();
        #pragma unroll
        for (int kk = 0; kk < 2; ++kk) {
            bf16x8 af[4], bfr[4];
            #pragma unroll
            for (int mi = 0; mi < 4; ++mi) {
                int row = wr + mi * 16 + r16;
                int slot = (kk * 4 + g) ^ (row & 7);
                af[mi] = *reinterpret_cast<const bf16x8*>(&As[row * 64 + slot * 8]);
            }
            #pragma unroll
            for (int ni = 0; ni < 4; ++ni) {
                int row = wc + ni * 16 + r16;
                int slot = (kk * 4 + g) ^ (row & 7);
                bfr[ni] = *reinterpret_cast<const bf16x8*>(&Bs[row * 64 + slot * 8]);
            }
            #pragma unroll
            for (int mi = 0; mi < 4; ++mi)
                #pragma unroll
                for (int ni = 0; ni < 4; ++ni)
                    acc[mi][ni] = __builtin_amdgcn_mfma_f32_16x16x32_bf16(
                        af[mi], bfr[ni], acc[mi][ni], 0, 0, 0);
        }
        __syncthreads();
    }
    #pragma unroll
    for (int mi = 0; mi < 4; ++mi)
        #pragma unroll
        for (int q = 0; q < 4; ++q) {
            int row = bm + wr + mi * 16 + g * 4 + q;
            #pragma unroll
            for (int ni = 0; ni < 4; ++ni)
                C[(size_t)row * N + bn + wc + ni * 16 + r16] = acc[mi][ni][q];
        }
}

__global__ __launch_bounds__(256) void reduce4_kernel(float* __restrict__ out,
                                                      const float* __restrict__ p0,
                                                      const float* __restrict__ p1,
                                                      const float* __restrict__ p2,
                                                      const float* __restrict__ p3) {
    size_t i = ((size_t)blockIdx.x * 256 + threadIdx.x) * 4;
    float4 o = *reinterpret_cast<float4*>(&out[i]);
    float4 a = *reinterpret_cast<const float4*>(&p0[i]);
    float4 b = *reinterpret_cast<const float4*>(&p1[i]);
    float4 c = *reinterpret_cast<const float4*>(&p2[i]);
    float4 d = *reinterpret_cast<const float4*>(&p3[i]);
    o.x += a.x + b.x + c.x + d.x;
    o.y += a.y + b.y + c.y + d.y;
    o.z += a.z + b.z + c.z + d.z;
    o.w += a.w + b.w + c.w + d.w;
    *reinterpret_cast<float4*>(&out[i]) = o;
}

// ---------------- bf16x3 GEMM (fp32-equivalent): k = h @ Wk ----------------
__global__ __launch_bounds__(256) void gemm_k3(const unsigned short* __restrict__ A0,
                                               const unsigned short* __restrict__ A1,
                                               const unsigned short* __restrict__ A2,
                                               const unsigned short* __restrict__ B0,
                                               const unsigned short* __restrict__ B1,
                                               const unsigned short* __restrict__ B2,
                                               float* __restrict__ C,
                                               int M, int N, int K) {
    __shared__ __align__(16) short As[3][64 * 64];
    __shared__ __align__(16) short Bs[3][64 * 64];
    const int tid = threadIdx.x;
    const int wv = tid >> 6, ln = tid & 63;
    const int bm = blockIdx.y << 6, bn = blockIdx.x << 6;
    const int wr = (wv >> 1) << 5, wc = (wv & 1) << 5;
    const int g = ln >> 4, r16 = ln & 15;

    f32x4 acc[2][2];
    #pragma unroll
    for (int i = 0; i < 2; ++i)
        #pragma unroll
        for (int j = 0; j < 2; ++j) acc[i][j] = (f32x4){0.f, 0.f, 0.f, 0.f};

    const short* Ag[3] = {(const short*)A0, (const short*)A1, (const short*)A2};
    const short* Bg[3] = {(const short*)B0, (const short*)B1, (const short*)B2};
    const int PA[6] = {0, 0, 1, 1, 0, 2};
    const int PB[6] = {0, 1, 0, 1, 2, 0};

    const int srow_off = ln >> 3;
    const int sslot = ln & 7;
    for (int k0 = 0; k0 < K; k0 += 64) {
        #pragma unroll
        for (int p = 0; p < 3; ++p) {
            #pragma unroll
            for (int i = 0; i < 2; ++i) {
                int c = wv * 2 + i;
                int row = c * 8 + srow_off;
                int kcol = ((sslot ^ (row & 7)) << 3);
                gload_lds16(Ag[p] + (size_t)(bm + row) * K + k0 + kcol, &As[p][c * 512 + ln * 8]);
                gload_lds16(Bg[p] + (size_t)(bn + row) * K + k0 + kcol, &Bs[p][c * 512 + ln * 8]);
            }
        }
        __syncthreads();
        #pragma unroll
        for (int kk = 0; kk < 2; ++kk) {
            bf16x8 af[3][2], bfr[3][2];
            #pragma unroll
            for (int p = 0; p < 3; ++p) {
                #pragma unroll
                for (int mi = 0; mi < 2; ++mi) {
                    int row = wr + mi * 16 + r16;
                    int slot = (kk * 4 + g) ^ (row & 7);
                    af[p][mi] = *reinterpret_cast<const bf16x8*>(&As[p][row * 64 + slot * 8]);
                }
                #pragma unroll
                for (int ni = 0; ni < 2; ++ni) {
                    int row = wc + ni * 16 + r16;
                    int slot = (kk * 4 + g) ^ (row & 7);
                    bfr[p][ni] = *reinterpret_cast<const bf16x8*>(&Bs[p][row * 64 + slot * 8]);
                }
            }
            #pragma unroll
            for (int pp = 0; pp < 6; ++pp) {
                #pragma unroll
                for (int mi = 0; mi < 2; ++mi)
                    #pragma unroll
                    for (int ni = 0; ni < 2; ++ni)
                        acc[mi][ni] = __builtin_amdgcn_mfma_f32_16x16x32_bf16(
                            af[PA[pp]][mi], bfr[PB[pp]][ni], acc[mi][ni], 0, 0, 0);
            }
        }
        __syncthreads();
    }
    #pragma unroll
    for (int mi = 0; mi < 2; ++mi)
        #pragma unroll
        for (int q = 0; q < 4; ++q) {
            int row = bm + wr + mi * 16 + g * 4 + q;
            #pragma unroll
            for (int ni = 0; ni < 2; ++ni)
                C[(size_t)row * N + bn + wc + ni * 16 + r16] = acc[mi][ni][q];
        }
}

// ---------------- dual-B SwiGLU GEMM, 128x128 tile ----------------
__global__ __launch_bounds__(256) void gemm_swiglu_bf16(const unsigned short* __restrict__ A,
                                                        const unsigned short* __restrict__ B1t,
                                                        const unsigned short* __restrict__ B2t,
                                                        unsigned short* __restrict__ G,
                                                        int M, int N, int K) {
    __shared__ __align__(16) short As[128 * 64];
    __shared__ __align__(16) short Bs1[128 * 64];
    __shared__ __align__(16) short Bs2[128 * 64];
    const int tid = threadIdx.x;
    const int wv = tid >> 6, ln = tid & 63;
    const int bm = blockIdx.y << 7, bn = blockIdx.x << 7;
    const int wr = (wv >> 1) << 6, wc = (wv & 1) << 6;
    const int g = ln >> 4, r16 = ln & 15;

    f32x4 acc1[4][4], acc2[4][4];
    #pragma unroll
    for (int i = 0; i < 4; ++i)
        #pragma unroll
        for (int j = 0; j < 4; ++j) {
            acc1[i][j] = (f32x4){0.f, 0.f, 0.f, 0.f};
            acc2[i][j] = (f32x4){0.f, 0.f, 0.f, 0.f};
        }

    const short* Ag = (const short*)A;
    const short* B1g = (const short*)B1t;
    const short* B2g = (const short*)B2t;
    const int srow_off = ln >> 3;
    const int sslot = ln & 7;
    for (int k0 = 0; k0 < K; k0 += 64) {
        #pragma unroll
        for (int i = 0; i < 4; ++i) {
            int c = wv * 4 + i;
            int row = c * 8 + srow_off;
            int kcol = ((sslot ^ (row & 7)) << 3);
            gload_lds16(Ag + (size_t)(bm + row) * K + k0 + kcol, &As[c * 512 + ln * 8]);
            gload_lds16(B1g + (size_t)(bn + row) * K + k0 + kcol, &Bs1[c * 512 + ln * 8]);
            gload_lds16(B2g + (size_t)(bn + row) * K + k0 + kcol, &Bs2[c * 512 + ln * 8]);
        }
        __syncthreads();
        #pragma unroll
        for (int kk = 0; kk < 2; ++kk) {
            bf16x8 af[4], b1f[4], b2f[4];
            #pragma unroll
            for (int mi = 0; mi < 4; ++mi) {
                int row = wr + mi * 16 + r16;
                int slot = (kk * 4 + g) ^ (row & 7);
                af[mi] = *reinterpret_cast<const bf16x8*>(&As[row * 64 + slot * 8]);
            }
            #pragma unroll
            for (int ni = 0; ni < 4; ++ni) {
                int row = wc + ni * 16 + r16;
                int slot = (kk * 4 + g) ^ (row & 7);
                b1f[ni] = *reinterpret_cast<const bf16x8*>(&Bs1[row * 64 + slot * 8]);
                b2f[ni] = *reinterpret_cast<const bf16x8*>(&Bs2[row * 64 + slot * 8]);
            }
            #pragma unroll
            for (int mi = 0; mi < 4; ++mi)
                #pragma unroll
                for (int ni = 0; ni < 4; ++ni) {
                    acc1[mi][ni] = __builtin_amdgcn_mfma_f32_16x16x32_bf16(
                        af[mi], b1f[ni], acc1[mi][ni], 0, 0, 0);
                    acc2[mi][ni] = __builtin_amdgcn_mfma_f32_16x16x32_bf16(
                        af[mi], b2f[ni], acc2[mi][ni], 0, 0, 0);
                }
        }
        __syncthreads();
    }
    #pragma unroll
    for (int mi = 0; mi < 4; ++mi)
        #pragma unroll
        for (int q = 0; q < 4; ++q) {
            int row = bm + wr + mi * 16 + g * 4 + q;
            #pragma unroll
            for (int ni = 0; ni < 4; ++ni) {
                int col = bn + wc + ni * 16 + r16;
                float a = acc1[mi][ni][q];
                float vv = a / (1.0f + expf(-a)) * acc2[mi][ni][q];
                G[(size_t)row * N + col] = f2bf(vv);
            }
        }
}

// ---------------- spike + kWTA (fp32 in, bf16 out) ----------------
__global__ __launch_bounds__(256) void kwta_kernel(const float* __restrict__ kin,
                                                   unsigned short* __restrict__ k16,
                                                   int total) {
    int wid = (int)((blockIdx.x * (size_t)blockDim.x + threadIdx.x) >> 6);
    int lane = threadIdx.x & 63;
    if (wid >= total) return;
    float v = kin[(size_t)wid * HD + lane];
    float val = (v > 0.5f) ? v : 0.0f;
    float cur = val;
    float thr = 0.0f;
    #pragma unroll
    for (int it = 0; it < 4; ++it) {
        float m = cur;
        #pragma unroll
        for (int off = 32; off; off >>= 1) m = fmaxf(m, __shfl_xor(m, off));
        thr = m;
        unsigned long long ball = __ballot(cur == m);
        int leader = __ffsll(ball) - 1;
        if (lane == leader) cur = -1.0f;
    }
    k16[(size_t)wid * HD + lane] = f2bf((val >= thr) ? val : 0.0f);
}

// ---------------- attention pass A (MFMA): CT[e][d] = sum_l v[l][e]*kw[l][d] ----------------
__global__ __launch_bounds__(256) void attn_state_mfma(const unsigned short* __restrict__ vTg,
                                                       const unsigned short* __restrict__ kwTg,
                                                       float* __restrict__ Cbuf) {
    __shared__ __align__(16) short vT_l[64 * 128];
    __shared__ __align__(16) short kwT_l[64 * 128];
    const int tid = threadIdx.x, w = tid >> 6, ln = tid & 63;
    const int n = blockIdx.x >> 5, bh = blockIdx.x & 31;
    const int b = bh >> 4, h = bh & 15;
    const int g = ln >> 4, r = ln & 15;
    const short* vg = (const short*)vTg;
    const short* kg = (const short*)kwTg;
    #pragma unroll
    for (int i = 0; i < 4; ++i) {
        int c = w * 4 + i;
        int row = c * 4 + (ln >> 4);
        int gs = (ln & 15) ^ (row & 7);
        size_t go = (size_t)(b * 1024 + h * 64 + row) * 1024 + n * 128 + gs * 8;
        gload_lds16(vg + go, &vT_l[c * 512 + ln * 8]);
        gload_lds16(kg + go, &kwT_l[c * 512 + ln * 8]);
    }
    __syncthreads();
    f32x4 acc[4];
    #pragma unroll
    for (int i = 0; i < 4; ++i) acc[i] = (f32x4){0.f, 0.f, 0.f, 0.f};
    #pragma unroll
    for (int ks = 0; ks < 4; ++ks) {
        int row_e = w * 16 + r;
        int se = (ks * 4 + g) ^ (row_e & 7);
        bf16x8 av = *reinterpret_cast<const bf16x8*>(&vT_l[row_e * 128 + se * 8]);
        #pragma unroll
        for (int ni = 0; ni < 4; ++ni) {
            int row_d = ni * 16 + r;
            int sd = (ks * 4 + g) ^ (row_d & 7);
            bf16x8 bk = *reinterpret_cast<const bf16x8*>(&kwT_l[row_d * 128 + sd * 8]);
            acc[ni] = __builtin_amdgcn_mfma_f32_16x16x32_bf16(av, bk, acc[ni], 0, 0, 0);
        }
    }
    size_t base = (size_t)blockIdx.x * 4096;
    #pragma unroll
    for (int ni = 0; ni < 4; ++ni)
        #pragma unroll
        for (int q = 0; q < 4; ++q) {
            int e = w * 16 + g * 4 + q;
            int d = ni * 16 + r;
            Cbuf[base + e * 64 + d] = acc[ni][q];
        }
}

// ---------------- attention pass B: prefix scan, bf16 states out ----------------
__global__ __launch_bounds__(256) void attn_scan_kernel(const float* __restrict__ Cbuf,
                                                        unsigned short* __restrict__ STg) {
    int bh = blockIdx.x;
    int tid = threadIdx.x;
    float S[16];
    #pragma unroll
    for (int j = 0; j < 16; ++j) S[j] = 0.0f;
    for (int n = 0; n < NCHUNK; ++n) {
        size_t o = ((size_t)(n * 32 + bh)) * 4096 + tid * 16;
        #pragma unroll
        for (int j = 0; j < 16; ++j) STg[o + j] = f2bf(S[j]);
        #pragma unroll
        for (int j = 0; j < 16; ++j) S[j] = WL_128 * S[j] + Cbuf[o + j];
    }
}

// ---------------- attention pass C (MFMA): y = w_in*(r@S^T) + (mask(k@r^T))^T @ v ----------------
__global__ __launch_bounds__(256) void attn_out_mfma(const unsigned short* __restrict__ r16,
                                                     const unsigned short* __restrict__ k16,
                                                     const unsigned short* __restrict__ vTg,
                                                     const unsigned short* __restrict__ STg,
                                                     unsigned short* __restrict__ y) {
    __shared__ __align__(16) short r_l[128 * 64];
    __shared__ __align__(16) short k_l[128 * 64];
    __shared__ __align__(16) short vT_l[64 * 128];
    __shared__ __align__(16) short ST_l[64 * 64];
    __shared__ __align__(16) short PA_l[128 * 128];
    const int tid = threadIdx.x, w = tid >> 6, ln = tid & 63;
    const int n = blockIdx.x >> 5, bh = blockIdx.x & 31;
    const int b = bh >> 4, h = bh & 15;
    const int g = ln >> 4, r = ln & 15;
    const short* rg = (const short*)r16;
    const short* kg = (const short*)k16;
    const short* vg = (const short*)vTg;
    const short* sg = (const short*)STg;
    // stage r,k (128 rows x 64)
    #pragma unroll
    for (int i = 0; i < 4; ++i) {
        int c = w * 4 + i;
        int row = c * 8 + (ln >> 3);
        int gs = (ln & 7) ^ (row & 7);
        size_t go = (size_t)(b * 1024 + n * 128 + row) * 1024 + h * 64 + gs * 8;
        gload_lds16(rg + go, &r_l[c * 512 + ln * 8]);
        gload_lds16(kg + go, &k_l[c * 512 + ln * 8]);
    }
    // stage vT (64 rows x 128)
    #pragma unroll
    for (int i = 0; i < 4; ++i) {
        int c = w * 4 + i;
        int row = c * 4 + (ln >> 4);
        int gs = (ln & 15) ^ (row & 7);
        gload_lds16(vg + (size_t)(b * 1024 + h * 64 + row) * 1024 + n * 128 + gs * 8,
                    &vT_l[c * 512 + ln * 8]);
    }
    // stage ST (64 rows x 64)
    #pragma unroll
    for (int i = 0; i < 2; ++i) {
        int c = w * 2 + i;
        int row = c * 8 + (ln >> 3);
        int gs = (ln & 7) ^ (row & 7);
        gload_lds16(sg + (size_t)(n * 32 + bh) * 4096 + row * 64 + gs * 8,
                    &ST_l[c * 512 + ln * 8]);
    }
    __syncthreads();
    // pass 1: S_mat[m][l] = k[m].r[l]  (wave w: m in [32w, 32w+32))
    f32x4 sacc[2][8];
    #pragma unroll
    for (int i = 0; i < 2; ++i)
        #pragma unroll
        for (int j = 0; j < 8; ++j) sacc[i][j] = (f32x4){0.f, 0.f, 0.f, 0.f};
    #pragma unroll
    for (int kk = 0; kk < 2; ++kk) {
        bf16x8 am[2];
        #pragma unroll
        for (int mi = 0; mi < 2; ++mi) {
            int row_m = w * 32 + mi * 16 + r;
            int s = (kk * 4 + g) ^ (row_m & 7);
            am[mi] = *reinterpret_cast<const bf16x8*>(&k_l[row_m * 64 + s * 8]);
        }
        #pragma unroll
        for (int li = 0; li < 8; ++li) {
            int row_l = li * 16 + r;
            int s = (kk * 4 + g) ^ (row_l & 7);
            bf16x8 bl = *reinterpret_cast<const bf16x8*>(&r_l[row_l * 64 + s * 8]);
            #pragma unroll
            for (int mi = 0; mi < 2; ++mi)
                sacc[mi][li] = __builtin_amdgcn_mfma_f32_16x16x32_bf16(am[mi], bl, sacc[mi][li], 0, 0, 0);
        }
    }
    // mask + bf16 pack -> PA[l][m]
    #pragma unroll
    for (int mi = 0; mi < 2; ++mi) {
        #pragma unroll
        for (int li = 0; li < 8; ++li) {
            int l = li * 16 + r;
            int mb = w * 32 + mi * 16 + g * 4;
            ushort4 pv;
            unsigned short* pk = (unsigned short*)&pv;
            #pragma unroll
            for (int q = 0; q < 4; ++q) {
                int m = mb + q;
                float f = 0.0f;
                if (l >= m) f = sacc[mi][li][q] * exp2f((float)(l - m) * LOG2D);
                pk[q] = f2bf(f);
            }
            int slot = (mb >> 3) ^ (l & 7);
            *reinterpret_cast<ushort4*>((char*)PA_l + l * 256 + slot * 16 + (mb & 7) * 2) = pv;
        }
    }
    // pass 2: inter = r @ ST^T  (wave w: l in [32w, 32w+32))
    f32x4 yacc[2][4];
    #pragma unroll
    for (int i = 0; i < 2; ++i)
        #pragma unroll
        for (int j = 0; j < 4; ++j) yacc[i][j] = (f32x4){0.f, 0.f, 0.f, 0.f};
    #pragma unroll
    for (int kk = 0; kk < 2; ++kk) {
        bf16x8 ar[2];
        #pragma unroll
        for (int mi = 0; mi < 2; ++mi) {
            int row_l = w * 32 + mi * 16 + r;
            int s = (kk * 4 + g) ^ (row_l & 7);
            ar[mi] = *reinterpret_cast<const bf16x8*>(&r_l[row_l * 64 + s * 8]);
        }
        #pragma unroll
        for (int ei = 0; ei < 4; ++ei) {
            int row_e = ei * 16 + r;
            int s = (kk * 4 + g) ^ (row_e & 7);
            bf16x8 be = *reinterpret_cast<const bf16x8*>(&ST_l[row_e * 64 + s * 8]);
            #pragma unroll
            for (int mi = 0; mi < 2; ++mi)
                yacc[mi][ei] = __builtin_amdgcn_mfma_f32_16x16x32_bf16(ar[mi], be, yacc[mi][ei], 0, 0, 0);
        }
    }
    // scale inter by w_in[l] = decay^(l+1)
    #pragma unroll
    for (int mi = 0; mi < 2; ++mi)
        #pragma unroll
        for (int q = 0; q < 4; ++q) {
            int l = w * 32 + mi * 16 + g * 4 + q;
            float win = exp2f((float)(l + 1) * LOG2D);
            #pragma unroll
            for (int ei = 0; ei < 4; ++ei) yacc[mi][ei][q] *= win;
        }
    __syncthreads();
    // pass 3: intra = PA @ vT^T
    #pragma unroll
    for (int ks = 0; ks < 4; ++ks) {
        bf16x8 ap[2];
        #pragma unroll
        for (int mi = 0; mi < 2; ++mi) {
            int row_l = w * 32 + mi * 16 + r;
            int s = (ks * 4 + g) ^ (row_l & 7);
            ap[mi] = *reinterpret_cast<const bf16x8*>(&PA_l[row_l * 128 + s * 8]);
        }
        #pragma unroll
        for (int ei = 0; ei < 4; ++ei) {
            int row_e = ei * 16 + r;
            int s = (ks * 4 + g) ^ (row_e & 7);
            bf16x8 bv = *reinterpret_cast<const bf16x8*>(&vT_l[row_e * 128 + s * 8]);
            #pragma unroll
            for (int mi = 0; mi < 2; ++mi)
                yacc[mi][ei] = __builtin_amdgcn_mfma_f32_16x16x32_bf16(ap[mi], bv, yacc[mi][ei], 0, 0, 0);
        }
    }
    // store y[l][e] bf16
    #pragma unroll
    for (int mi = 0; mi < 2; ++mi)
        #pragma unroll
        for (int q = 0; q < 4; ++q) {
            int l = w * 32 + mi * 16 + g * 4 + q;
            size_t base = (size_t)(b * 1024 + n * 128 + l) * 1024 + h * 64;
            #pragma unroll
            for (int ei = 0; ei < 4; ++ei)
                y[base + ei * 16 + r] = f2bf(yacc[mi][ei][q]);
        }
}

extern "C" void kernel_launch(void* const* d_in, const int* in_sizes, int n_in,
                              void* d_out, int out_size, void* d_ws, size_t ws_size,
                              hipStream_t stream) {
    const float* x      = (const float*)d_in[0];
    const float* norm1w = (const float*)d_in[1];
    const float* Wr     = (const float*)d_in[2];
    const float* Wk     = (const float*)d_in[3];
    const float* Wv     = (const float*)d_in[4];
    const float* Wo     = (const float*)d_in[5];
    const float* norm2w = (const float*)d_in[6];
    const float* w1     = (const float*)d_in[7];
    const float* w2     = (const float*)d_in[8];
    const float* w3     = (const float*)d_in[9];
    float* out = (float*)d_out;
    char* ws = (char*)d_ws;
    (void)in_sizes; (void)n_in; (void)out_size; (void)ws_size;

    const size_t MB = 1048576;
    unsigned short* wr_t = (unsigned short*)(ws + 0 * MB);
    unsigned short* wv_t = (unsigned short*)(ws + 2 * MB);
    unsigned short* wo_t = (unsigned short*)(ws + 4 * MB);
    unsigned short* w1_t = (unsigned short*)(ws + 6 * MB);
    unsigned short* w2_t = (unsigned short*)(ws + 14 * MB);
    unsigned short* w3_t = (unsigned short*)(ws + 22 * MB);
    unsigned short* wk0  = (unsigned short*)(ws + 30 * MB);
    unsigned short* wk1  = (unsigned short*)(ws + 32 * MB);
    unsigned short* wk2  = (unsigned short*)(ws + 34 * MB);
    unsigned short* h0   = (unsigned short*)(ws + 36 * MB);
    unsigned short* h1   = (unsigned short*)(ws + 40 * MB);
    unsigned short* h2   = (unsigned short*)(ws + 44 * MB);
    unsigned short* r16  = (unsigned short*)(ws + 48 * MB);
    float*          kbuf = (float*)(ws + 52 * MB);           // 8 MB fp32
    unsigned short* k16  = (unsigned short*)(ws + 60 * MB);
    unsigned short* v16  = (unsigned short*)(ws + 64 * MB);
    unsigned short* vTg  = (unsigned short*)(ws + 68 * MB);
    unsigned short* kwTg = (unsigned short*)(ws + 72 * MB);  // peak 76 MB
    float*          Cbuf = (float*)(ws + 40 * MB);           // over h1 (dead post-k3)
    unsigned short* STg  = (unsigned short*)(ws + 44 * MB);  // over h2 (dead post-k3)
    unsigned short* y16  = (unsigned short*)(ws + 52 * MB);  // over kbuf (dead post-kwta)
    // MLP phase:
    unsigned short* h0b  = (unsigned short*)(ws + 36 * MB);  // over h0
    unsigned short* g16  = (unsigned short*)(ws + 40 * MB);  // 16 MB, over Cbuf/STg/r16
    float*          p01  = (float*)(ws + 6 * MB);            // 16 MB, over w1_t/w2_t
    float*          p23  = (float*)(ws + 56 * MB);           // 16 MB, over k16/v16/vTg...

    dim3 blk(256);

    transpose_w<<<dim3(16, 16), blk, 0, stream>>>(Wr, wr_t, DIMD, DIMD);
    transpose_w<<<dim3(16, 16), blk, 0, stream>>>(Wv, wv_t, DIMD, DIMD);
    transpose_w<<<dim3(16, 16), blk, 0, stream>>>(Wo, wo_t, DIMD, DIMD);
    transpose_w<<<dim3(64, 16), blk, 0, stream>>>(w1, w1_t, DIMD, HIDDEN);
    transpose_w<<<dim3(64, 16), blk, 0, stream>>>(w2, w2_t, DIMD, HIDDEN);
    transpose_w<<<dim3(16, 64), blk, 0, stream>>>(w3, w3_t, HIDDEN, DIMD);
    transpose_cvt3<<<dim3(16, 16), blk, 0, stream>>>(Wk, wk0, wk1, wk2, DIMD, DIMD);

    rmsnorm_kernel<<<BT, blk, 0, stream>>>(x, norm1w, h0, h1, h2);
    gemm_bf16<4><<<dim3(8, 16), blk, 0, stream>>>(h0, wr_t, r16, nullptr, BT, DIMD, DIMD);
    gemm_k3<<<dim3(16, 32), blk, 0, stream>>>(h0, h1, h2, wk0, wk1, wk2, kbuf, BT, DIMD, DIMD);
    kwta_kernel<<<(BT * HEADS) / 4, blk, 0, stream>>>(kbuf, k16, BT * HEADS);
    gemm_bf16<3><<<dim3(8, 16), blk, 0, stream>>>(h0, wv_t, v16, nullptr, BT, DIMD, DIMD);
    transpose_attn<<<dim3(16, 16, 2), blk, 0, stream>>>(v16, vTg, 0);
    transpose_attn<<<dim3(16, 16, 2), blk, 0, stream>>>(k16, kwTg, 1);
    attn_state_mfma<<<NCHUNK * 32, blk, 0, stream>>>(vTg, kwTg, Cbuf);
    attn_scan_kernel<<<32, blk, 0, stream>>>(Cbuf, STg);
    attn_out_mfma<<<NCHUNK * 32, blk, 0, stream>>>(r16, k16, vTg, STg, y16);
    gemm_bf16<2><<<dim3(8, 16), blk, 0, stream>>>(y16, wo_t, out, x, BT, DIMD, DIMD);
    rmsnorm_kernel<<<BT, blk, 0, stream>>>(out, norm2w, h0b, nullptr, nullptr);
    gemm_swiglu_bf16<<<dim3(32, 16), blk, 0, stream>>>(h0b, w1_t, w2_t, g16, BT, HIDDEN, DIMD);
    gemm_splitk<<<dim3(8, 16, 4), blk, 0, stream>>>(g16, w3_t, p01, p23, BT, DIMD, HIDDEN);
    reduce4_kernel<<<2048, blk, 0, stream>>>(out, p01, p01 + (size_t)BT * DIMD,
                                             p23, p23 + (size_t)BT * DIMD);
}

// Round 6
// 213.864 us; speedup vs baseline: 7.3119x; 1.2418x over previous
//
#include <hip/hip_runtime.h>
#include <hip/hip_bf16.h>
#include <math.h>

// AURA block. B=2, T=1024, D=1024, H=16, HD=64, chunk L=128, N=8, HIDDEN=4096.
// Round 6: k = [h0|h0|h1]@[wk0|wk1|wk0] single GEMM with fused kWTA epilogue;
// mega projection launch (r|v + k paths co-scheduled); single prep kernel
// (7 transposes + rmsnorm1); BM=64 Wo GEMM; merged attn transposes.

#define DIMD 1024
#define BT   2048
#define HEADS 16
#define HD   64
#define CHUNK 128
#define NCHUNK 8
#define HIDDEN 4096
#define WL_128 1.3900845e-06f           // 0.9^128
#define LOG2D  (-0.15200309344504997f)  // log2(0.9)

typedef __attribute__((ext_vector_type(4))) float f32x4;
typedef __attribute__((ext_vector_type(8))) short bf16x8;

__device__ __forceinline__ unsigned short f2bf(float f) {
    __hip_bfloat16 h = __float2bfloat16(f);
    return __builtin_bit_cast(unsigned short, h);
}
__device__ __forceinline__ float bf2f(unsigned short u) {
    __hip_bfloat16 h = __builtin_bit_cast(__hip_bfloat16, u);
    return __bfloat162float(h);
}
__device__ __forceinline__ void gload_lds16(const void* g, void* l) {
    __builtin_amdgcn_global_load_lds(
        (const __attribute__((address_space(1))) void*)g,
        (__attribute__((address_space(3))) void*)l,
        16, 0, 0);
}

// ================= prep kernel: 7 weight transposes + rmsnorm1 =================
// blocks 0..4095: transposes (64x64 tiles). blocks 4096..6143: rmsnorm rows.
__global__ __launch_bounds__(256) void prep_kernel(const float* __restrict__ x,
                                                   const float* __restrict__ norm1w,
                                                   const float* __restrict__ Wr,
                                                   const float* __restrict__ Wv,
                                                   const float* __restrict__ Wo,
                                                   const float* __restrict__ Wk,
                                                   const float* __restrict__ w1,
                                                   const float* __restrict__ w2,
                                                   const float* __restrict__ w3,
                                                   unsigned short* __restrict__ BtA,
                                                   unsigned short* __restrict__ wo_t,
                                                   unsigned short* __restrict__ wkB,
                                                   unsigned short* __restrict__ w1t,
                                                   unsigned short* __restrict__ w2t,
                                                   unsigned short* __restrict__ w3t,
                                                   unsigned short* __restrict__ hI) {
    __shared__ float t[64][65];
    __shared__ float red[4];
    int bid = blockIdx.x;
    if (bid < 4096) {
        const float* src; unsigned short* dst; int K, N, tile, mode = 0;
        if (bid < 256)       { src = Wr; dst = BtA;                 K = 1024; N = 1024; tile = bid; }
        else if (bid < 512)  { src = Wv; dst = BtA + 1024 * 1024;   K = 1024; N = 1024; tile = bid - 256; }
        else if (bid < 768)  { src = Wo; dst = wo_t;                K = 1024; N = 1024; tile = bid - 512; }
        else if (bid < 1024) { src = Wk; dst = wkB;                 K = 1024; N = 1024; tile = bid - 768; mode = 1; }
        else if (bid < 2048) { src = w1; dst = w1t; K = 1024; N = 4096; tile = bid - 1024; }
        else if (bid < 3072) { src = w2; dst = w2t; K = 1024; N = 4096; tile = bid - 2048; }
        else                 { src = w3; dst = w3t; K = 4096; N = 1024; tile = bid - 3072; }
        int xt = N >> 6;
        int bn = (tile % xt) << 6, bk = (tile / xt) << 6;
        int tx = threadIdx.x & 15, ty = threadIdx.x >> 4;
        #pragma unroll
        for (int i = 0; i < 4; ++i) {
            float4 v = *reinterpret_cast<const float4*>(&src[(size_t)(bk + ty + i * 16) * N + bn + tx * 4]);
            t[ty + i * 16][tx * 4 + 0] = v.x;
            t[ty + i * 16][tx * 4 + 1] = v.y;
            t[ty + i * 16][tx * 4 + 2] = v.z;
            t[ty + i * 16][tx * 4 + 3] = v.w;
        }
        __syncthreads();
        #pragma unroll
        for (int i = 0; i < 4; ++i) {
            int nrow = ty + i * 16;
            if (mode == 0) {
                ushort4 o;
                o.x = f2bf(t[tx * 4 + 0][nrow]);
                o.y = f2bf(t[tx * 4 + 1][nrow]);
                o.z = f2bf(t[tx * 4 + 2][nrow]);
                o.w = f2bf(t[tx * 4 + 3][nrow]);
                *reinterpret_cast<ushort4*>(&dst[(size_t)(bn + nrow) * K + bk + tx * 4]) = o;
            } else {
                // Wk: row n of wkB = [wk0 | wk1 | wk0], K'=3072
                ushort4 o0, o1;
                unsigned short* p0 = (unsigned short*)&o0;
                unsigned short* p1 = (unsigned short*)&o1;
                #pragma unroll
                for (int j = 0; j < 4; ++j) {
                    float val = t[tx * 4 + j][nrow];
                    unsigned short b0 = f2bf(val);
                    p0[j] = b0;
                    p1[j] = f2bf(val - bf2f(b0));
                }
                size_t rb = (size_t)(bn + nrow) * 3072;
                *reinterpret_cast<ushort4*>(&wkB[rb + bk + tx * 4]) = o0;
                *reinterpret_cast<ushort4*>(&wkB[rb + 1024 + bk + tx * 4]) = o1;
                *reinterpret_cast<ushort4*>(&wkB[rb + 2048 + bk + tx * 4]) = o0;
            }
        }
    } else {
        // rmsnorm1: hI row = [bf16(h) | bf16(h - bf16(h))]
        int row = bid - 4096;
        const float* xr = x + (size_t)row * DIMD;
        int i0 = threadIdx.x * 4;
        float4 v = *reinterpret_cast<const float4*>(xr + i0);
        float ss = v.x*v.x + v.y*v.y + v.z*v.z + v.w*v.w;
        #pragma unroll
        for (int off = 32; off; off >>= 1) ss += __shfl_xor(ss, off);
        if ((threadIdx.x & 63) == 0) red[threadIdx.x >> 6] = ss;
        __syncthreads();
        ss = red[0] + red[1] + red[2] + red[3];
        float norm = rsqrtf(ss * (1.0f / DIMD) + 1e-5f);
        float4 wv = *reinterpret_cast<const float4*>(norm1w + i0);
        float o[4];
        o[0] = wv.x * v.x * norm; o[1] = wv.y * v.y * norm;
        o[2] = wv.z * v.z * norm; o[3] = wv.w * v.w * norm;
        ushort4 u0, u1;
        unsigned short* q0 = (unsigned short*)&u0;
        unsigned short* q1 = (unsigned short*)&u1;
        #pragma unroll
        for (int j = 0; j < 4; ++j) {
            q0[j] = f2bf(o[j]);
            q1[j] = f2bf(o[j] - bf2f(q0[j]));
        }
        *reinterpret_cast<ushort4*>(hI + (size_t)row * 2048 + i0) = u0;
        *reinterpret_cast<ushort4*>(hI + (size_t)row * 2048 + 1024 + i0) = u1;
    }
}

// ================= mega projection kernel =================
// blocks 0..255:   path A: [r|v] = h0 @ BtA^T (128x128 tile, K=1024, lda=2048)
// blocks 256..511: path B: k = [h0|h0|h1] @ wkB^T (64x128 tile, K=3072) + spike/kWTA
__global__ __launch_bounds__(256) void proj_kernel(const unsigned short* __restrict__ hI,
                                                   const unsigned short* __restrict__ BtA,
                                                   const unsigned short* __restrict__ wkB,
                                                   unsigned short* __restrict__ r16,
                                                   unsigned short* __restrict__ v16,
                                                   unsigned short* __restrict__ k16) {
    __shared__ __align__(16) short As[128 * 64];
    __shared__ __align__(16) short Bs[128 * 64];
    const int tid = threadIdx.x;
    const int wv = tid >> 6, ln = tid & 63;
    const int g = ln >> 4, r = ln & 15;
    const int srow_off = ln >> 3;
    const int sslot = ln & 7;
    const short* Ag = (const short*)hI;

    if (blockIdx.x < 256) {
        // ---- path A ----
        const int bx = blockIdx.x & 15, by = blockIdx.x >> 4;
        const int bm = by << 7, bn = bx << 7;
        const int wr = (wv >> 1) << 6, wc = (wv & 1) << 6;
        const short* Bg = (const short*)BtA;
        f32x4 acc[4][4];
        #pragma unroll
        for (int i = 0; i < 4; ++i)
            #pragma unroll
            for (int j = 0; j < 4; ++j) acc[i][j] = (f32x4){0.f, 0.f, 0.f, 0.f};
        for (int k0 = 0; k0 < 1024; k0 += 64) {
            #pragma unroll
            for (int i = 0; i < 4; ++i) {
                int c = wv * 4 + i;
                int row = c * 8 + srow_off;
                int kcol = ((sslot ^ (row & 7)) << 3);
                gload_lds16(Ag + (size_t)(bm + row) * 2048 + k0 + kcol, &As[c * 512 + ln * 8]);
                gload_lds16(Bg + (size_t)(bn + row) * 1024 + k0 + kcol, &Bs[c * 512 + ln * 8]);
            }
            __syncthreads();
            #pragma unroll
            for (int kk = 0; kk < 2; ++kk) {
                bf16x8 af[4], bfr[4];
                #pragma unroll
                for (int mi = 0; mi < 4; ++mi) {
                    int row = wr + mi * 16 + r;
                    int slot = (kk * 4 + g) ^ (row & 7);
                    af[mi] = *reinterpret_cast<const bf16x8*>(&As[row * 64 + slot * 8]);
                }
                #pragma unroll
                for (int ni = 0; ni < 4; ++ni) {
                    int row = wc + ni * 16 + r;
                    int slot = (kk * 4 + g) ^ (row & 7);
                    bfr[ni] = *reinterpret_cast<const bf16x8*>(&Bs[row * 64 + slot * 8]);
                }
                #pragma unroll
                for (int mi = 0; mi < 4; ++mi)
                    #pragma unroll
                    for (int ni = 0; ni < 4; ++ni)
                        acc[mi][ni] = __builtin_amdgcn_mfma_f32_16x16x32_bf16(
                            af[mi], bfr[ni], acc[mi][ni], 0, 0, 0);
            }
            __syncthreads();
        }
        #pragma unroll
        for (int mi = 0; mi < 4; ++mi)
            #pragma unroll
            for (int q = 0; q < 4; ++q) {
                int row = bm + wr + mi * 16 + g * 4 + q;
                #pragma unroll
                for (int ni = 0; ni < 4; ++ni) {
                    int col = bn + wc + ni * 16 + r;
                    float vv = acc[mi][ni][q];
                    if (col < 1024) {
                        r16[(size_t)row * 1024 + col] = f2bf(1.0f / (1.0f + expf(-vv)));
                    } else {
                        v16[(size_t)row * 1024 + col - 1024] = f2bf(vv);
                    }
                }
            }
    } else {
        // ---- path B: k + fused spike/kWTA ----
        const int id = blockIdx.x - 256;
        const int bx = id & 7, by = id >> 3;         // 8 n-tiles x 32 m-tiles
        const int bm = by << 6, bn = bx << 7;
        const int wr = (wv >> 1) << 5, wc = (wv & 1) << 6;
        const short* Bg = (const short*)wkB;
        f32x4 acc[2][4];
        #pragma unroll
        for (int i = 0; i < 2; ++i)
            #pragma unroll
            for (int j = 0; j < 4; ++j) acc[i][j] = (f32x4){0.f, 0.f, 0.f, 0.f};
        for (int k0 = 0; k0 < 3072; k0 += 64) {
            int srck0 = (k0 >= 1024) ? (k0 - 1024) : k0;   // [h0|h0|h1] within hI row
            #pragma unroll
            for (int i = 0; i < 2; ++i) {
                int c = wv * 2 + i;
                int row = c * 8 + srow_off;
                int kcol = ((sslot ^ (row & 7)) << 3);
                gload_lds16(Ag + (size_t)(bm + row) * 2048 + srck0 + kcol, &As[c * 512 + ln * 8]);
            }
            #pragma unroll
            for (int i = 0; i < 4; ++i) {
                int c = wv * 4 + i;
                int row = c * 8 + srow_off;
                int kcol = ((sslot ^ (row & 7)) << 3);
                gload_lds16(Bg + (size_t)(bn + row) * 3072 + k0 + kcol, &Bs[c * 512 + ln * 8]);
            }
            __syncthreads();
            #pragma unroll
            for (int kk = 0; kk < 2; ++kk) {
                bf16x8 af[2], bfr[4];
                #pragma unroll
                for (int mi = 0; mi < 2; ++mi) {
                    int row = wr + mi * 16 + r;
                    int slot = (kk * 4 + g) ^ (row & 7);
                    af[mi] = *reinterpret_cast<const bf16x8*>(&As[row * 64 + slot * 8]);
                }
                #pragma unroll
                for (int ni = 0; ni < 4; ++ni) {
                    int row = wc + ni * 16 + r;
                    int slot = (kk * 4 + g) ^ (row & 7);
                    bfr[ni] = *reinterpret_cast<const bf16x8*>(&Bs[row * 64 + slot * 8]);
                }
                #pragma unroll
                for (int mi = 0; mi < 2; ++mi)
                    #pragma unroll
                    for (int ni = 0; ni < 4; ++ni)
                        acc[mi][ni] = __builtin_amdgcn_mfma_f32_16x16x32_bf16(
                            af[mi], bfr[ni], acc[mi][ni], 0, 0, 0);
            }
            __syncthreads();
        }
        // epilogue: spike threshold + k-winners-take-all per row (64-col head per wave)
        const unsigned long long gmask = 0xFFFFULL << (g * 16);
        #pragma unroll
        for (int mi = 0; mi < 2; ++mi) {
            #pragma unroll
            for (int q = 0; q < 4; ++q) {
                float s[4], cur[4];
                #pragma unroll
                for (int ni = 0; ni < 4; ++ni) {
                    float a = acc[mi][ni][q];
                    s[ni] = (a > 0.5f) ? a : 0.0f;
                    cur[ni] = s[ni];
                }
                float thr = 0.0f;
                #pragma unroll
                for (int it = 0; it < 4; ++it) {
                    float lm = fmaxf(fmaxf(cur[0], cur[1]), fmaxf(cur[2], cur[3]));
                    float gm = lm;
                    #pragma unroll
                    for (int off = 1; off < 16; off <<= 1) gm = fmaxf(gm, __shfl_xor(gm, off));
                    thr = gm;
                    unsigned long long ball = __ballot(lm == gm) & gmask;
                    int leader = __ffsll(ball) - 1;
                    if (ln == leader) {
                        bool done = false;
                        #pragma unroll
                        for (int ni = 0; ni < 4; ++ni) {
                            if (!done && cur[ni] == gm) { cur[ni] = -1.0f; done = true; }
                        }
                    }
                }
                int row = bm + wr + mi * 16 + g * 4 + q;
                #pragma unroll
                for (int ni = 0; ni < 4; ++ni) {
                    float o = (s[ni] >= thr) ? s[ni] : 0.0f;
                    k16[(size_t)row * 1024 + bn + wc + ni * 16 + r] = f2bf(o);
                }
            }
        }
    }
}

// ================= merged attention-operand transpose =================
// z<2: vTg[b=z] (unscaled); z>=2: kwTg[b=z-2] (w_out decay fused)
__global__ __launch_bounds__(256) void transpose_attn4(const unsigned short* __restrict__ v16,
                                                       const unsigned short* __restrict__ k16,
                                                       unsigned short* __restrict__ vTg,
                                                       unsigned short* __restrict__ kwTg) {
    __shared__ float t[64][65];
    int z = blockIdx.z;
    const unsigned short* src = (z < 2) ? v16 : k16;
    unsigned short* dst = (z < 2) ? vTg : kwTg;
    int b = z & 1;
    int scaled = (z >= 2);
    int bc = blockIdx.x * 64, bt = blockIdx.y * 64;
    int tx = threadIdx.x & 15, ty = threadIdx.x >> 4;
    #pragma unroll
    for (int i = 0; i < 4; ++i) {
        ushort4 v = *reinterpret_cast<const ushort4*>(&src[(size_t)(b * 1024 + bt + ty + i * 16) * 1024 + bc + tx * 4]);
        t[ty + i * 16][tx * 4 + 0] = bf2f(v.x);
        t[ty + i * 16][tx * 4 + 1] = bf2f(v.y);
        t[ty + i * 16][tx * 4 + 2] = bf2f(v.z);
        t[ty + i * 16][tx * 4 + 3] = bf2f(v.w);
    }
    __syncthreads();
    #pragma unroll
    for (int i = 0; i < 4; ++i) {
        int crow = ty + i * 16;
        ushort4 o;
        unsigned short* po = (unsigned short*)&o;
        #pragma unroll
        for (int j = 0; j < 4; ++j) {
            int tl = bt + tx * 4 + j;
            float sc = scaled ? exp2f((float)(127 - (tl & 127)) * LOG2D) : 1.0f;
            po[j] = f2bf(t[tx * 4 + j][crow] * sc);
        }
        *reinterpret_cast<ushort4*>(&dst[(size_t)(b * 1024 + bc + crow) * 1024 + bt + tx * 4]) = o;
    }
}

// ================= generic bf16 GEMM: C[M,N] = A @ Bt^T =================
// EPI: 0 fp32, 2 +add fp32, 3 bf16.  MI: 4 -> BM=128, 2 -> BM=64.
template <int EPI, int MI>
__global__ __launch_bounds__(256) void gemm_bf16(const unsigned short* __restrict__ A,
                                                 const unsigned short* __restrict__ Bt,
                                                 void* __restrict__ Cout,
                                                 const float* __restrict__ add,
                                                 int M, int N, int K) {
    __shared__ __align__(16) short As[MI * 32 * 64];
    __shared__ __align__(16) short Bs[128 * 64];
    const int tid = threadIdx.x;
    const int wv = tid >> 6, ln = tid & 63;
    const int bm = blockIdx.y * (MI * 32), bn = blockIdx.x << 7;
    const int wr = (wv >> 1) * (MI * 16), wc = (wv & 1) << 6;
    const int g = ln >> 4, r16 = ln & 15;

    f32x4 acc[MI][4];
    #pragma unroll
    for (int i = 0; i < MI; ++i)
        #pragma unroll
        for (int j = 0; j < 4; ++j) acc[i][j] = (f32x4){0.f, 0.f, 0.f, 0.f};

    const short* Ag = (const short*)A;
    const short* Bg = (const short*)Bt;
    const int srow_off = ln >> 3;
    const int sslot = ln & 7;
    for (int k0 = 0; k0 < K; k0 += 64) {
        #pragma unroll
        for (int i = 0; i < MI; ++i) {
            int c = wv * MI + i;
            int row = c * 8 + srow_off;
            int kcol = ((sslot ^ (row & 7)) << 3);
            gload_lds16(Ag + (size_t)(bm + row) * K + k0 + kcol, &As[c * 512 + ln * 8]);
        }
        #pragma unroll
        for (int i = 0; i < 4; ++i) {
            int c = wv * 4 + i;
            int row = c * 8 + srow_off;
            int kcol = ((sslot ^ (row & 7)) << 3);
            gload_lds16(Bg + (size_t)(bn + row) * K + k0 + kcol, &Bs[c * 512 + ln * 8]);
        }
        __syncthreads();
        #pragma unroll
        for (int kk = 0; kk < 2; ++kk) {
            bf16x8 af[MI], bfr[4];
            #pragma unroll
            for (int mi = 0; mi < MI; ++mi) {
                int row = wr + mi * 16 + r16;
                int slot = (kk * 4 + g) ^ (row & 7);
                af[mi] = *reinterpret_cast<const bf16x8*>(&As[row * 64 + slot * 8]);
            }
            #pragma unroll
            for (int ni = 0; ni < 4; ++ni) {
                int row = wc + ni * 16 + r16;
                int slot = (kk * 4 + g) ^ (row & 7);
                bfr[ni] = *reinterpret_cast<const bf16x8*>(&Bs[row * 64 + slot * 8]);
            }
            #pragma unroll
            for (int mi = 0; mi < MI; ++mi)
                #pragma unroll
                for (int ni = 0; ni < 4; ++ni)
                    acc[mi][ni] = __builtin_amdgcn_mfma_f32_16x16x32_bf16(
                        af[mi], bfr[ni], acc[mi][ni], 0, 0, 0);
        }
        __syncthreads();
    }
    #pragma unroll
    for (int mi = 0; mi < MI; ++mi)
        #pragma unroll
        for (int q = 0; q < 4; ++q) {
            int row = bm + wr + mi * 16 + g * 4 + q;
            #pragma unroll
            for (int ni = 0; ni < 4; ++ni) {
                int col = bn + wc + ni * 16 + r16;
                float vv = acc[mi][ni][q];
                size_t o = (size_t)row * N + col;
                if (EPI == 2) vv += add[o];
                if (EPI == 3) ((unsigned short*)Cout)[o] = f2bf(vv);
                else          ((float*)Cout)[o] = vv;
            }
        }
}

// ================= split-K GEMM (w3) =================
__global__ __launch_bounds__(256) void gemm_splitk(const unsigned short* __restrict__ A,
                                                   const unsigned short* __restrict__ Bt,
                                                   float* __restrict__ P01,
                                                   float* __restrict__ P23,
                                                   int M, int N, int lda) {
    __shared__ __align__(16) short As[128 * 64];
    __shared__ __align__(16) short Bs[128 * 64];
    const int tid = threadIdx.x;
    const int wv = tid >> 6, ln = tid & 63;
    const int bm = blockIdx.y << 7, bn = blockIdx.x << 7;
    const int z = blockIdx.z;
    const int wr = (wv >> 1) << 6, wc = (wv & 1) << 6;
    const int g = ln >> 4, r16 = ln & 15;
    float* C = (z < 2) ? (P01 + (size_t)z * M * N) : (P23 + (size_t)(z - 2) * M * N);

    f32x4 acc[4][4];
    #pragma unroll
    for (int i = 0; i < 4; ++i)
        #pragma unroll
        for (int j = 0; j < 4; ++j) acc[i][j] = (f32x4){0.f, 0.f, 0.f, 0.f};

    const short* Ag = (const short*)A + z * 1024;
    const short* Bg = (const short*)Bt + z * 1024;
    const int srow_off = ln >> 3;
    const int sslot = ln & 7;
    for (int k0 = 0; k0 < 1024; k0 += 64) {
        #pragma unroll
        for (int i = 0; i < 4; ++i) {
            int c = wv * 4 + i;
            int row = c * 8 + srow_off;
            int kcol = ((sslot ^ (row & 7)) << 3);
            gload_lds16(Ag + (size_t)(bm + row) * lda + k0 + kcol, &As[c * 512 + ln * 8]);
            gload_lds16(Bg + (size_t)(bn + row) * lda + k0 + kcol, &Bs[c * 512 + ln * 8]);
        }
        __syncthreads();
        #pragma unroll
        for (int kk = 0; kk < 2; ++kk) {
            bf16x8 af[4], bfr[4];
            #pragma unroll
            for (int mi = 0; mi < 4; ++mi) {
                int row = wr + mi * 16 + r16;
                int slot = (kk * 4 + g) ^ (row & 7);
                af[mi] = *reinterpret_cast<const bf16x8*>(&As[row * 64 + slot * 8]);
            }
            #pragma unroll
            for (int ni = 0; ni < 4; ++ni) {
                int row = wc + ni * 16 + r16;
                int slot = (kk * 4 + g) ^ (row & 7);
                bfr[ni] = *reinterpret_cast<const bf16x8*>(&Bs[row * 64 + slot * 8]);
            }
            #pragma unroll
            for (int mi = 0; mi < 4; ++mi)
                #pragma unroll
                for (int ni = 0; ni < 4; ++ni)
                    acc[mi][ni] = __builtin_amdgcn_mfma_f32_16x16x32_bf16(
                        af[mi], bfr[ni], acc[mi][ni], 0, 0, 0);
        }
        __syncthreads();
    }
    #pragma unroll
    for (int mi = 0; mi < 4; ++mi)
        #pragma unroll
        for (int q = 0; q < 4; ++q) {
            int row = bm + wr + mi * 16 + g * 4 + q;
            #pragma unroll
            for (int ni = 0; ni < 4; ++ni)
                C[(size_t)row * N + bn + wc + ni * 16 + r16] = acc[mi][ni][q];
        }
}

__global__ __launch_bounds__(256) void reduce4_kernel(float* __restrict__ out,
                                                      const float* __restrict__ p0,
                                                      const float* __restrict__ p1,
                                                      const float* __restrict__ p2,
                                                      const float* __restrict__ p3) {
    size_t i = ((size_t)blockIdx.x * 256 + threadIdx.x) * 4;
    float4 o = *reinterpret_cast<float4*>(&out[i]);
    float4 a = *reinterpret_cast<const float4*>(&p0[i]);
    float4 b = *reinterpret_cast<const float4*>(&p1[i]);
    float4 c = *reinterpret_cast<const float4*>(&p2[i]);
    float4 d = *reinterpret_cast<const float4*>(&p3[i]);
    o.x += a.x + b.x + c.x + d.x;
    o.y += a.y + b.y + c.y + d.y;
    o.z += a.z + b.z + c.z + d.z;
    o.w += a.w + b.w + c.w + d.w;
    *reinterpret_cast<float4*>(&out[i]) = o;
}

// ================= dual-B SwiGLU GEMM, 128x128 =================
__global__ __launch_bounds__(256) void gemm_swiglu_bf16(const unsigned short* __restrict__ A,
                                                        const unsigned short* __restrict__ B1t,
                                                        const unsigned short* __restrict__ B2t,
                                                        unsigned short* __restrict__ G,
                                                        int M, int N, int K) {
    __shared__ __align__(16) short As[128 * 64];
    __shared__ __align__(16) short Bs1[128 * 64];
    __shared__ __align__(16) short Bs2[128 * 64];
    const int tid = threadIdx.x;
    const int wv = tid >> 6, ln = tid & 63;
    const int bm = blockIdx.y << 7, bn = blockIdx.x << 7;
    const int wr = (wv >> 1) << 6, wc = (wv & 1) << 6;
    const int g = ln >> 4, r16 = ln & 15;

    f32x4 acc1[4][4], acc2[4][4];
    #pragma unroll
    for (int i = 0; i < 4; ++i)
        #pragma unroll
        for (int j = 0; j < 4; ++j) {
            acc1[i][j] = (f32x4){0.f, 0.f, 0.f, 0.f};
            acc2[i][j] = (f32x4){0.f, 0.f, 0.f, 0.f};
        }

    const short* Ag = (const short*)A;
    const short* B1g = (const short*)B1t;
    const short* B2g = (const short*)B2t;
    const int srow_off = ln >> 3;
    const int sslot = ln & 7;
    for (int k0 = 0; k0 < K; k0 += 64) {
        #pragma unroll
        for (int i = 0; i < 4; ++i) {
            int c = wv * 4 + i;
            int row = c * 8 + srow_off;
            int kcol = ((sslot ^ (row & 7)) << 3);
            gload_lds16(Ag + (size_t)(bm + row) * K + k0 + kcol, &As[c * 512 + ln * 8]);
            gload_lds16(B1g + (size_t)(bn + row) * K + k0 + kcol, &Bs1[c * 512 + ln * 8]);
            gload_lds16(B2g + (size_t)(bn + row) * K + k0 + kcol, &Bs2[c * 512 + ln * 8]);
        }
        __syncthreads();
        #pragma unroll
        for (int kk = 0; kk < 2; ++kk) {
            bf16x8 af[4], b1f[4], b2f[4];
            #pragma unroll
            for (int mi = 0; mi < 4; ++mi) {
                int row = wr + mi * 16 + r16;
                int slot = (kk * 4 + g) ^ (row & 7);
                af[mi] = *reinterpret_cast<const bf16x8*>(&As[row * 64 + slot * 8]);
            }
            #pragma unroll
            for (int ni = 0; ni < 4; ++ni) {
                int row = wc + ni * 16 + r16;
                int slot = (kk * 4 + g) ^ (row & 7);
                b1f[ni] = *reinterpret_cast<const bf16x8*>(&Bs1[row * 64 + slot * 8]);
                b2f[ni] = *reinterpret_cast<const bf16x8*>(&Bs2[row * 64 + slot * 8]);
            }
            #pragma unroll
            for (int mi = 0; mi < 4; ++mi)
                #pragma unroll
                for (int ni = 0; ni < 4; ++ni) {
                    acc1[mi][ni] = __builtin_amdgcn_mfma_f32_16x16x32_bf16(
                        af[mi], b1f[ni], acc1[mi][ni], 0, 0, 0);
                    acc2[mi][ni] = __builtin_amdgcn_mfma_f32_16x16x32_bf16(
                        af[mi], b2f[ni], acc2[mi][ni], 0, 0, 0);
                }
        }
        __syncthreads();
    }
    #pragma unroll
    for (int mi = 0; mi < 4; ++mi)
        #pragma unroll
        for (int q = 0; q < 4; ++q) {
            int row = bm + wr + mi * 16 + g * 4 + q;
            #pragma unroll
            for (int ni = 0; ni < 4; ++ni) {
                int col = bn + wc + ni * 16 + r16;
                float a = acc1[mi][ni][q];
                float vv = a / (1.0f + expf(-a)) * acc2[mi][ni][q];
                G[(size_t)row * N + col] = f2bf(vv);
            }
        }
}

// ================= rmsnorm2 (bf16 out) =================
__global__ __launch_bounds__(256) void rms2_kernel(const float* __restrict__ x,
                                                   const float* __restrict__ w,
                                                   unsigned short* __restrict__ h) {
    int row = blockIdx.x;
    const float* xr = x + (size_t)row * DIMD;
    int i0 = threadIdx.x * 4;
    float4 v = *reinterpret_cast<const float4*>(xr + i0);
    float ss = v.x*v.x + v.y*v.y + v.z*v.z + v.w*v.w;
    #pragma unroll
    for (int off = 32; off; off >>= 1) ss += __shfl_xor(ss, off);
    __shared__ float red[4];
    if ((threadIdx.x & 63) == 0) red[threadIdx.x >> 6] = ss;
    __syncthreads();
    ss = red[0] + red[1] + red[2] + red[3];
    float norm = rsqrtf(ss * (1.0f / DIMD) + 1e-5f);
    float4 wv = *reinterpret_cast<const float4*>(w + i0);
    ushort4 u;
    u.x = f2bf(wv.x * v.x * norm);
    u.y = f2bf(wv.y * v.y * norm);
    u.z = f2bf(wv.z * v.z * norm);
    u.w = f2bf(wv.w * v.w * norm);
    *reinterpret_cast<ushort4*>(h + (size_t)row * DIMD + i0) = u;
}

// ================= attention kernels (as R5) =================
__global__ __launch_bounds__(256) void attn_state_mfma(const unsigned short* __restrict__ vTg,
                                                       const unsigned short* __restrict__ kwTg,
                                                       float* __restrict__ Cbuf) {
    __shared__ __align__(16) short vT_l[64 * 128];
    __shared__ __align__(16) short kwT_l[64 * 128];
    const int tid = threadIdx.x, w = tid >> 6, ln = tid & 63;
    const int n = blockIdx.x >> 5, bh = blockIdx.x & 31;
    const int b = bh >> 4, h = bh & 15;
    const int g = ln >> 4, r = ln & 15;
    const short* vg = (const short*)vTg;
    const short* kg = (const short*)kwTg;
    #pragma unroll
    for (int i = 0; i < 4; ++i) {
        int c = w * 4 + i;
        int row = c * 4 + (ln >> 4);
        int gs = (ln & 15) ^ (row & 7);
        size_t go = (size_t)(b * 1024 + h * 64 + row) * 1024 + n * 128 + gs * 8;
        gload_lds16(vg + go, &vT_l[c * 512 + ln * 8]);
        gload_lds16(kg + go, &kwT_l[c * 512 + ln * 8]);
    }
    __syncthreads();
    f32x4 acc[4];
    #pragma unroll
    for (int i = 0; i < 4; ++i) acc[i] = (f32x4){0.f, 0.f, 0.f, 0.f};
    #pragma unroll
    for (int ks = 0; ks < 4; ++ks) {
        int row_e = w * 16 + r;
        int se = (ks * 4 + g) ^ (row_e & 7);
        bf16x8 av = *reinterpret_cast<const bf16x8*>(&vT_l[row_e * 128 + se * 8]);
        #pragma unroll
        for (int ni = 0; ni < 4; ++ni) {
            int row_d = ni * 16 + r;
            int sd = (ks * 4 + g) ^ (row_d & 7);
            bf16x8 bk = *reinterpret_cast<const bf16x8*>(&kwT_l[row_d * 128 + sd * 8]);
            acc[ni] = __builtin_amdgcn_mfma_f32_16x16x32_bf16(av, bk, acc[ni], 0, 0, 0);
        }
    }
    size_t base = (size_t)blockIdx.x * 4096;
    #pragma unroll
    for (int ni = 0; ni < 4; ++ni)
        #pragma unroll
        for (int q = 0; q < 4; ++q) {
            int e = w * 16 + g * 4 + q;
            int d = ni * 16 + r;
            Cbuf[base + e * 64 + d] = acc[ni][q];
        }
}

__global__ __launch_bounds__(256) void attn_scan_kernel(const float* __restrict__ Cbuf,
                                                        unsigned short* __restrict__ STg) {
    int bh = blockIdx.x;
    int tid = threadIdx.x;
    float S[16];
    #pragma unroll
    for (int j = 0; j < 16; ++j) S[j] = 0.0f;
    for (int n = 0; n < NCHUNK; ++n) {
        size_t o = ((size_t)(n * 32 + bh)) * 4096 + tid * 16;
        #pragma unroll
        for (int j = 0; j < 16; ++j) STg[o + j] = f2bf(S[j]);
        #pragma unroll
        for (int j = 0; j < 16; ++j) S[j] = WL_128 * S[j] + Cbuf[o + j];
    }
}

__global__ __launch_bounds__(256) void attn_out_mfma(const unsigned short* __restrict__ r16,
                                                     const unsigned short* __restrict__ k16,
                                                     const unsigned short* __restrict__ vTg,
                                                     const unsigned short* __restrict__ STg,
                                                     unsigned short* __restrict__ y) {
    __shared__ __align__(16) short r_l[128 * 64];
    __shared__ __align__(16) short k_l[128 * 64];
    __shared__ __align__(16) short vT_l[64 * 128];
    __shared__ __align__(16) short ST_l[64 * 64];
    __shared__ __align__(16) short PA_l[128 * 128];
    const int tid = threadIdx.x, w = tid >> 6, ln = tid & 63;
    const int n = blockIdx.x >> 5, bh = blockIdx.x & 31;
    const int b = bh >> 4, h = bh & 15;
    const int g = ln >> 4, r = ln & 15;
    const short* rg = (const short*)r16;
    const short* kg = (const short*)k16;
    const short* vg = (const short*)vTg;
    const short* sg = (const short*)STg;
    #pragma unroll
    for (int i = 0; i < 4; ++i) {
        int c = w * 4 + i;
        int row = c * 8 + (ln >> 3);
        int gs = (ln & 7) ^ (row & 7);
        size_t go = (size_t)(b * 1024 + n * 128 + row) * 1024 + h * 64 + gs * 8;
        gload_lds16(rg + go, &r_l[c * 512 + ln * 8]);
        gload_lds16(kg + go, &k_l[c * 512 + ln * 8]);
    }
    #pragma unroll
    for (int i = 0; i < 4; ++i) {
        int c = w * 4 + i;
        int row = c * 4 + (ln >> 4);
        int gs = (ln & 15) ^ (row & 7);
        gload_lds16(vg + (size_t)(b * 1024 + h * 64 + row) * 1024 + n * 128 + gs * 8,
                    &vT_l[c * 512 + ln * 8]);
    }
    #pragma unroll
    for (int i = 0; i < 2; ++i) {
        int c = w * 2 + i;
        int row = c * 8 + (ln >> 3);
        int gs = (ln & 7) ^ (row & 7);
        gload_lds16(sg + (size_t)(n * 32 + bh) * 4096 + row * 64 + gs * 8,
                    &ST_l[c * 512 + ln * 8]);
    }
    __syncthreads();
    f32x4 sacc[2][8];
    #pragma unroll
    for (int i = 0; i < 2; ++i)
        #pragma unroll
        for (int j = 0; j < 8; ++j) sacc[i][j] = (f32x4){0.f, 0.f, 0.f, 0.f};
    #pragma unroll
    for (int kk = 0; kk < 2; ++kk) {
        bf16x8 am[2];
        #pragma unroll
        for (int mi = 0; mi < 2; ++mi) {
            int row_m = w * 32 + mi * 16 + r;
            int s = (kk * 4 + g) ^ (row_m & 7);
            am[mi] = *reinterpret_cast<const bf16x8*>(&k_l[row_m * 64 + s * 8]);
        }
        #pragma unroll
        for (int li = 0; li < 8; ++li) {
            int row_l = li * 16 + r;
            int s = (kk * 4 + g) ^ (row_l & 7);
            bf16x8 bl = *reinterpret_cast<const bf16x8*>(&r_l[row_l * 64 + s * 8]);
            #pragma unroll
            for (int mi = 0; mi < 2; ++mi)
                sacc[mi][li] = __builtin_amdgcn_mfma_f32_16x16x32_bf16(am[mi], bl, sacc[mi][li], 0, 0, 0);
        }
    }
    #pragma unroll
    for (int mi = 0; mi < 2; ++mi) {
        #pragma unroll
        for (int li = 0; li < 8; ++li) {
            int l = li * 16 + r;
            int mb = w * 32 + mi * 16 + g * 4;
            ushort4 pv;
            unsigned short* pk = (unsigned short*)&pv;
            #pragma unroll
            for (int q = 0; q < 4; ++q) {
                int m = mb + q;
                float f = 0.0f;
                if (l >= m) f = sacc[mi][li][q] * exp2f((float)(l - m) * LOG2D);
                pk[q] = f2bf(f);
            }
            int slot = (mb >> 3) ^ (l & 7);
            *reinterpret_cast<ushort4*>((char*)PA_l + l * 256 + slot * 16 + (mb & 7) * 2) = pv;
        }
    }
    f32x4 yacc[2][4];
    #pragma unroll
    for (int i = 0; i < 2; ++i)
        #pragma unroll
        for (int j = 0; j < 4; ++j) yacc[i][j] = (f32x4){0.f, 0.f, 0.f, 0.f};
    #pragma unroll
    for (int kk = 0; kk < 2; ++kk) {
        bf16x8 ar[2];
        #pragma unroll
        for (int mi = 0; mi < 2; ++mi) {
            int row_l = w * 32 + mi * 16 + r;
            int s = (kk * 4 + g) ^ (row_l & 7);
            ar[mi] = *reinterpret_cast<const bf16x8*>(&r_l[row_l * 64 + s * 8]);
        }
        #pragma unroll
        for (int ei = 0; ei < 4; ++ei) {
            int row_e = ei * 16 + r;
            int s = (kk * 4 + g) ^ (row_e & 7);
            bf16x8 be = *reinterpret_cast<const bf16x8*>(&ST_l[row_e * 64 + s * 8]);
            #pragma unroll
            for (int mi = 0; mi < 2; ++mi)
                yacc[mi][ei] = __builtin_amdgcn_mfma_f32_16x16x32_bf16(ar[mi], be, yacc[mi][ei], 0, 0, 0);
        }
    }
    #pragma unroll
    for (int mi = 0; mi < 2; ++mi)
        #pragma unroll
        for (int q = 0; q < 4; ++q) {
            int l = w * 32 + mi * 16 + g * 4 + q;
            float win = exp2f((float)(l + 1) * LOG2D);
            #pragma unroll
            for (int ei = 0; ei < 4; ++ei) yacc[mi][ei][q] *= win;
        }
    __syncthreads();
    #pragma unroll
    for (int ks = 0; ks < 4; ++ks) {
        bf16x8 ap[2];
        #pragma unroll
        for (int mi = 0; mi < 2; ++mi) {
            int row_l = w * 32 + mi * 16 + r;
            int s = (ks * 4 + g) ^ (row_l & 7);
            ap[mi] = *reinterpret_cast<const bf16x8*>(&PA_l[row_l * 128 + s * 8]);
        }
        #pragma unroll
        for (int ei = 0; ei < 4; ++ei) {
            int row_e = ei * 16 + r;
            int s = (ks * 4 + g) ^ (row_e & 7);
            bf16x8 bv = *reinterpret_cast<const bf16x8*>(&vT_l[row_e * 128 + s * 8]);
            #pragma unroll
            for (int mi = 0; mi < 2; ++mi)
                yacc[mi][ei] = __builtin_amdgcn_mfma_f32_16x16x32_bf16(ap[mi], bv, yacc[mi][ei], 0, 0, 0);
        }
    }
    #pragma unroll
    for (int mi = 0; mi < 2; ++mi)
        #pragma unroll
        for (int q = 0; q < 4; ++q) {
            int l = w * 32 + mi * 16 + g * 4 + q;
            size_t base = (size_t)(b * 1024 + n * 128 + l) * 1024 + h * 64;
            #pragma unroll
            for (int ei = 0; ei < 4; ++ei)
                y[base + ei * 16 + r] = f2bf(yacc[mi][ei][q]);
        }
}

extern "C" void kernel_launch(void* const* d_in, const int* in_sizes, int n_in,
                              void* d_out, int out_size, void* d_ws, size_t ws_size,
                              hipStream_t stream) {
    const float* x      = (const float*)d_in[0];
    const float* norm1w = (const float*)d_in[1];
    const float* Wr     = (const float*)d_in[2];
    const float* Wk     = (const float*)d_in[3];
    const float* Wv     = (const float*)d_in[4];
    const float* Wo     = (const float*)d_in[5];
    const float* norm2w = (const float*)d_in[6];
    const float* w1     = (const float*)d_in[7];
    const float* w2     = (const float*)d_in[8];
    const float* w3     = (const float*)d_in[9];
    float* out = (float*)d_out;
    char* ws = (char*)d_ws;
    (void)in_sizes; (void)n_in; (void)out_size; (void)ws_size;

    const size_t MB = 1048576;
    unsigned short* BtA  = (unsigned short*)(ws + 0 * MB);   // 4 MB  [2048][1024] wr|wv
    unsigned short* wkB  = (unsigned short*)(ws + 4 * MB);   // 6 MB  [1024][3072]
    unsigned short* wo_t = (unsigned short*)(ws + 10 * MB);  // 2 MB
    unsigned short* w1t  = (unsigned short*)(ws + 12 * MB);  // 8 MB
    unsigned short* w2t  = (unsigned short*)(ws + 20 * MB);  // 8 MB
    unsigned short* w3t  = (unsigned short*)(ws + 28 * MB);  // 8 MB
    unsigned short* hI   = (unsigned short*)(ws + 36 * MB);  // 8 MB  [2048][2048] h0|h1
    unsigned short* r16  = (unsigned short*)(ws + 44 * MB);  // 4 MB
    unsigned short* v16  = (unsigned short*)(ws + 48 * MB);  // 4 MB
    unsigned short* k16  = (unsigned short*)(ws + 52 * MB);  // 4 MB
    unsigned short* vTg  = (unsigned short*)(ws + 56 * MB);  // 4 MB
    unsigned short* kwTg = (unsigned short*)(ws + 60 * MB);  // 4 MB
    float*          Cbuf = (float*)(ws + 64 * MB);           // 4 MB
    unsigned short* STg  = (unsigned short*)(ws + 68 * MB);  // 2 MB
    unsigned short* y16  = (unsigned short*)(ws + 70 * MB);  // 4 MB (peak 74 MB)
    // MLP phase (after Wo GEMM):
    unsigned short* h0b  = (unsigned short*)(ws + 36 * MB);  // 4 MB (over hI)
    unsigned short* g16  = (unsigned short*)(ws + 56 * MB);  // 16 MB (over vTg..y16)
    float*          p01  = (float*)(ws + 12 * MB);           // 16 MB (over w1t/w2t, dead post-swiglu)
    float*          p23  = (float*)(ws + 40 * MB);           // 16 MB (over hI-tail/r16/v16/k16)

    dim3 blk(256);

    // 1. prep: all weight transposes + rmsnorm1 (one launch)
    prep_kernel<<<6144, blk, 0, stream>>>(x, norm1w, Wr, Wv, Wo, Wk, w1, w2, w3,
                                          BtA, wo_t, wkB, w1t, w2t, w3t, hI);
    // 2. projections: r|v (path A) + k with fused spike/kWTA (path B)
    proj_kernel<<<512, blk, 0, stream>>>(hI, BtA, wkB, r16, v16, k16);
    // 3. attention operand transposes (one launch)
    transpose_attn4<<<dim3(16, 16, 4), blk, 0, stream>>>(v16, k16, vTg, kwTg);
    // 4-6. attention
    attn_state_mfma<<<NCHUNK * 32, blk, 0, stream>>>(vTg, kwTg, Cbuf);
    attn_scan_kernel<<<32, blk, 0, stream>>>(Cbuf, STg);
    attn_out_mfma<<<NCHUNK * 32, blk, 0, stream>>>(r16, k16, vTg, STg, y16);
    // 7. out = x + y @ Wo  (BM=64 -> 256 blocks)
    gemm_bf16<2, 2><<<dim3(8, 32), blk, 0, stream>>>(y16, wo_t, out, x, BT, DIMD, DIMD);
    // 8. h = rmsnorm(out, norm2)
    rms2_kernel<<<BT, blk, 0, stream>>>(out, norm2w, h0b);
    // 9. g = silu(h@w1) * (h@w2)
    gemm_swiglu_bf16<<<dim3(32, 16), blk, 0, stream>>>(h0b, w1t, w2t, g16, BT, HIDDEN, DIMD);
    // 10-11. out += g @ w3 (split-K 4 + reduce)
    gemm_splitk<<<dim3(8, 16, 4), blk, 0, stream>>>(g16, w3t, p01, p23, BT, DIMD, HIDDEN);
    reduce4_kernel<<<2048, blk, 0, stream>>>(out, p01, p01 + (size_t)BT * DIMD,
                                             p23, p23 + (size_t)BT * DIMD);
}